// Round 1
// baseline (3272.906 us; speedup 1.0000x reference)
//
#include <hip/hip_runtime.h>
#include <cmath>

// Model dims (fixed)
#define LSEQ 100
#define NTOK 3200   // B*L = 32*100

// ---------------------------------------------------------------------------
// GEMM: C[M,N] = A[M,K] @ W[N,K]^T  (both operands K-major, "NT")
// BM=BN=64, BK=16, 64 threads, 8x8 microtile.
// mode 0: C = acc (+bias if given)
// mode 1: C = acc + bias + pos[row % LSEQ]
// mode 2: C += acc   (residual accumulate)
// Requires M%64==0, N%64==0. K arbitrary (vector path iff K%16==0).
// ---------------------------------------------------------------------------
__global__ __launch_bounds__(64)
void gemm_nt(const float* __restrict__ A, const float* __restrict__ W,
             float* __restrict__ C, int M, int N, int K,
             const float* __restrict__ bias, const float* __restrict__ pos,
             int mode) {
  __shared__ float As[16][64];
  __shared__ float Bs[16][64];
  const int tid = threadIdx.x;
  const int row0 = blockIdx.x * 64, col0 = blockIdx.y * 64;
  float acc[8][8];
#pragma unroll
  for (int i = 0; i < 8; ++i)
#pragma unroll
    for (int j = 0; j < 8; ++j) acc[i][j] = 0.f;

  const bool vec_ok = ((K & 15) == 0);
  for (int k0 = 0; k0 < K; k0 += 16) {
#pragma unroll
    for (int c = 0; c < 4; ++c) {
      const int chunk = tid + c * 64;   // 0..255
      const int r  = chunk >> 2;        // row/col within tile 0..63
      const int kc = (chunk & 3) << 2;  // k offset 0,4,8,12
      float a[4], w[4];
      if (vec_ok) {
        float4 av = *(const float4*)(A + (size_t)(row0 + r) * K + (k0 + kc));
        float4 wv = *(const float4*)(W + (size_t)(col0 + r) * K + (k0 + kc));
        a[0] = av.x; a[1] = av.y; a[2] = av.z; a[3] = av.w;
        w[0] = wv.x; w[1] = wv.y; w[2] = wv.z; w[3] = wv.w;
      } else {
#pragma unroll
        for (int jj = 0; jj < 4; ++jj) {
          int kk = k0 + kc + jj;
          a[jj] = (kk < K) ? A[(size_t)(row0 + r) * K + kk] : 0.f;
          w[jj] = (kk < K) ? W[(size_t)(col0 + r) * K + kk] : 0.f;
        }
      }
#pragma unroll
      for (int jj = 0; jj < 4; ++jj) { As[kc + jj][r] = a[jj]; Bs[kc + jj][r] = w[jj]; }
    }
    __syncthreads();
    const int tm = (tid & 7) * 8, tn = (tid >> 3) * 8;
#pragma unroll
    for (int k = 0; k < 16; ++k) {
      float av[8], bv[8];
      *(float4*)&av[0] = *(const float4*)&As[k][tm];
      *(float4*)&av[4] = *(const float4*)&As[k][tm + 4];
      *(float4*)&bv[0] = *(const float4*)&Bs[k][tn];
      *(float4*)&bv[4] = *(const float4*)&Bs[k][tn + 4];
#pragma unroll
      for (int i = 0; i < 8; ++i)
#pragma unroll
        for (int j = 0; j < 8; ++j)
          acc[i][j] += av[i] * bv[j];
    }
    __syncthreads();
  }
  const int tm = (tid & 7) * 8, tn = (tid >> 3) * 8;
#pragma unroll
  for (int i = 0; i < 8; ++i) {
    const int row = row0 + tm + i;
    float* crow = C + (size_t)row * N + (col0 + tn);
#pragma unroll
    for (int j = 0; j < 8; ++j) {
      float v = acc[i][j];
      if (bias) v += bias[col0 + tn + j];
      if (pos)  v += pos[(size_t)(row % LSEQ) * N + (col0 + tn + j)];
      if (mode == 2) v += crow[j];
      crow[j] = v;
    }
  }
}

// ---------------------------------------------------------------------------
// LayerNorm over 512 cols. One block (256 thr) per row. Input row stride
// parameterized so we can LN only the last-token rows at the end.
// ---------------------------------------------------------------------------
__global__ __launch_bounds__(256)
void ln_kernel(const float* __restrict__ x, float* __restrict__ o,
               const float* __restrict__ g, const float* __restrict__ b,
               long rowStride) {
  const int row = blockIdx.x, tid = threadIdx.x;
  const float* xr = x + (size_t)row * rowStride;
  float v0 = xr[tid], v1 = xr[tid + 256];
  float s = v0 + v1, ss = v0 * v0 + v1 * v1;
#pragma unroll
  for (int off = 32; off > 0; off >>= 1) {
    s  += __shfl_down(s, off, 64);
    ss += __shfl_down(ss, off, 64);
  }
  __shared__ float rs[4], rss[4], mb[2];
  const int wid = tid >> 6;
  if ((tid & 63) == 0) { rs[wid] = s; rss[wid] = ss; }
  __syncthreads();
  if (tid == 0) {
    float S = rs[0] + rs[1] + rs[2] + rs[3];
    float SS = rss[0] + rss[1] + rss[2] + rss[3];
    float m = S * (1.f / 512.f);
    float var = SS * (1.f / 512.f) - m * m;
    mb[0] = m; mb[1] = rsqrtf(var + 1e-5f);
  }
  __syncthreads();
  const float m = mb[0], r = mb[1];
  o[(size_t)row * 512 + tid]       = (v0 - m) * r * g[tid] + b[tid];
  o[(size_t)row * 512 + tid + 256] = (v1 - m) * r * g[tid + 256] + b[tid + 256];
}

// ---------------------------------------------------------------------------
// Depthwise causal conv (K=4) + bias + SiLU.  xp = xz[:, :1024].
// One thread per (t,d); grid = NTOK*1024/256.
// ---------------------------------------------------------------------------
__global__ __launch_bounds__(256)
void conv_kernel(const float* __restrict__ xz, const float* __restrict__ cw,
                 const float* __restrict__ cb, float* __restrict__ xc) {
  const int gid = blockIdx.x * 256 + threadIdx.x;
  const int d = gid & 1023;
  const int t = gid >> 10;
  const int b = t / LSEQ, l = t - b * LSEQ;
  const float4 w = *(const float4*)(cw + (size_t)d * 4);
  float acc = cb[d];
  const float* base = xz + (size_t)b * LSEQ * 2048 + d;
  const float wv[4] = {w.x, w.y, w.z, w.w};
#pragma unroll
  for (int k = 0; k < 4; ++k) {
    int ls = l - 3 + k;
    if (ls >= 0) acc += wv[k] * base[(size_t)ls * 2048];
  }
  xc[gid] = acc / (1.f + expf(-acc));
}

// ---------------------------------------------------------------------------
// xd[t, 0:64] = xc[t, :] @ xproj_w[64,1024]^T.  4 tokens per block (256 thr).
// ---------------------------------------------------------------------------
__global__ __launch_bounds__(256)
void xproj_kernel(const float* __restrict__ xc, const float* __restrict__ W,
                  float* __restrict__ xd) {
  __shared__ float sx[4][1024];
  __shared__ float red[4][4][64];  // [kq][token][j]
  const int tid = threadIdx.x;
  const size_t t0 = (size_t)blockIdx.x * 4;
  const float4* src = (const float4*)(xc + t0 * 1024);
  float4* dst = (float4*)sx;
#pragma unroll
  for (int i = 0; i < 4; ++i) dst[tid + i * 256] = src[tid + i * 256];
  __syncthreads();
  const int j = tid & 63, q = tid >> 6;
  const float* wr = W + (size_t)j * 1024 + q * 256;
  const float* s0 = &sx[0][q * 256];
  const float* s1 = &sx[1][q * 256];
  const float* s2 = &sx[2][q * 256];
  const float* s3 = &sx[3][q * 256];
  float p0 = 0, p1 = 0, p2 = 0, p3 = 0;
  for (int k = 0; k < 256; k += 4) {
    float4 wv = *(const float4*)(wr + k);
    p0 += wv.x * s0[k] + wv.y * s0[k + 1] + wv.z * s0[k + 2] + wv.w * s0[k + 3];
    p1 += wv.x * s1[k] + wv.y * s1[k + 1] + wv.z * s1[k + 2] + wv.w * s1[k + 3];
    p2 += wv.x * s2[k] + wv.y * s2[k + 1] + wv.z * s2[k + 2] + wv.w * s2[k + 3];
    p3 += wv.x * s3[k] + wv.y * s3[k + 1] + wv.z * s3[k + 2] + wv.w * s3[k + 3];
  }
  red[q][0][j] = p0; red[q][1][j] = p1; red[q][2][j] = p2; red[q][3][j] = p3;
  __syncthreads();
  const int tt = tid >> 6, jj = tid & 63;
  xd[(t0 + tt) * 64 + jj] =
      red[0][tt][jj] + red[1][tt][jj] + red[2][tt][jj] + red[3][tt][jj];
}

// ---------------------------------------------------------------------------
// dt[t,d] = softplus(xd[t,0:32] @ dt_w[d,:] + dt_b[d])
// ---------------------------------------------------------------------------
__global__ __launch_bounds__(256)
void dt_kernel(const float* __restrict__ xd, const float* __restrict__ dt_w,
               const float* __restrict__ dt_b, float* __restrict__ dt) {
  const int gid = blockIdx.x * 256 + threadIdx.x;
  const int t = gid >> 10, d = gid & 1023;
  const float* xr = xd + (size_t)t * 64;
  const float* wr = dt_w + (size_t)d * 32;
  float acc = dt_b[d];
#pragma unroll
  for (int r = 0; r < 32; r += 4) {
    float4 wv = *(const float4*)(wr + r);
    acc += wv.x * xr[r] + wv.y * xr[r + 1] + wv.z * xr[r + 2] + wv.w * xr[r + 3];
  }
  dt[gid] = (acc > 20.f) ? acc : log1pf(expf(acc));
}

// ---------------------------------------------------------------------------
// Selective scan. One thread per (b,d); 16 states in registers.
// y[t,d] = (sum_n h*C + Dp*xc) * silu(z)
// ---------------------------------------------------------------------------
__global__ __launch_bounds__(64)
void scan_kernel(const float* __restrict__ dt, const float* __restrict__ xc,
                 const float* __restrict__ xz, const float* __restrict__ xd,
                 const float* __restrict__ A_log, const float* __restrict__ Dp,
                 float* __restrict__ y) {
  const int b = blockIdx.x >> 4;
  const int d = ((blockIdx.x & 15) << 6) + threadIdx.x;
  float Av[16], h[16];
#pragma unroll
  for (int n = 0; n < 16; ++n) {
    Av[n] = -expf(A_log[(size_t)d * 16 + n]);
    h[n] = 0.f;
  }
  const float Dv = Dp[d];
  for (int t = 0; t < LSEQ; ++t) {
    const size_t tok = (size_t)b * LSEQ + t;
    const float dtv = dt[tok * 1024 + d];
    const float xcv = xc[tok * 1024 + d];
    const float zv  = xz[tok * 2048 + 1024 + d];
    const float dtxc = dtv * xcv;
    const float* xr = xd + tok * 64;
    float yv = 0.f;
#pragma unroll
    for (int n = 0; n < 16; ++n) {
      float dA = expf(dtv * Av[n]);
      h[n] = dA * h[n] + dtxc * xr[32 + n];
      yv += h[n] * xr[48 + n];
    }
    yv += Dv * xcv;
    yv *= zv / (1.f + expf(-zv));
    y[tok * 1024 + d] = yv;
  }
}

// ---------------------------------------------------------------------------
// Head: hid = gelu_exact(last @ op1_w^T + op1_b); out = hid @ op2_w^T + op2_b
// ---------------------------------------------------------------------------
__global__ __launch_bounds__(256)
void head1(const float* __restrict__ a, const float* __restrict__ W,
           const float* __restrict__ bias, float* __restrict__ o) {
  const int gid = blockIdx.x * 256 + threadIdx.x;  // 32*512
  const int bb = gid >> 9, m = gid & 511;
  const float* ar = a + (size_t)bb * 512;
  const float* wr = W + (size_t)m * 512;
  float acc = bias[m];
  for (int k = 0; k < 512; k += 4) {
    float4 av = *(const float4*)(ar + k);
    float4 wv = *(const float4*)(wr + k);
    acc += av.x * wv.x + av.y * wv.y + av.z * wv.z + av.w * wv.w;
  }
  o[gid] = 0.5f * acc * (1.f + erff(acc * 0.7071067811865475f));
}

__global__ __launch_bounds__(256)
void head2(const float* __restrict__ hid, const float* __restrict__ W,
           const float* __restrict__ bias, float* __restrict__ o) {
  const int gid = blockIdx.x * 256 + threadIdx.x;  // 32*128
  const int bb = gid >> 7, m = gid & 127;
  const float* ar = hid + (size_t)bb * 512;
  const float* wr = W + (size_t)m * 512;
  float acc = bias[m];
  for (int k = 0; k < 512; k += 4) {
    float4 av = *(const float4*)(ar + k);
    float4 wv = *(const float4*)(wr + k);
    acc += av.x * wv.x + av.y * wv.y + av.z * wv.z + av.w * wv.w;
  }
  o[gid] = acc;
}

// ---------------------------------------------------------------------------
extern "C" void kernel_launch(void* const* d_in, const int* in_sizes, int n_in,
                              void* d_out, int out_size, void* d_ws, size_t ws_size,
                              hipStream_t stream) {
  const float* x      = (const float*)d_in[0];
  const float* inp_w  = (const float*)d_in[1];
  const float* inp_b  = (const float*)d_in[2];
  const float* pos    = (const float*)d_in[3];
  const float* norm_g = (const float*)d_in[4];
  const float* norm_b = (const float*)d_in[5];
  const float* in_w   = (const float*)d_in[6];
  const float* conv_w = (const float*)d_in[7];
  const float* conv_b = (const float*)d_in[8];
  const float* xproj_w= (const float*)d_in[9];
  const float* dt_w   = (const float*)d_in[10];
  const float* dt_b   = (const float*)d_in[11];
  const float* A_log  = (const float*)d_in[12];
  const float* Dp     = (const float*)d_in[13];
  const float* out_w  = (const float*)d_in[14];
  const float* lnf_g  = (const float*)d_in[15];
  const float* lnf_b  = (const float*)d_in[16];
  const float* op1_w  = (const float*)d_in[17];
  const float* op1_b  = (const float*)d_in[18];
  const float* op2_w  = (const float*)d_in[19];
  const float* op2_b  = (const float*)d_in[20];
  float* out = (float*)d_out;

  // workspace layout (floats): ~79.6 MB total
  float* h      = (float*)d_ws;
  float* hn     = h      + (size_t)NTOK * 512;
  float* xz     = hn     + (size_t)NTOK * 512;
  float* xc     = xz     + (size_t)NTOK * 2048;
  float* xd     = xc     + (size_t)NTOK * 1024;
  float* dtb    = xd     + (size_t)NTOK * 64;
  float* yb     = dtb    + (size_t)NTOK * 1024;
  float* lastln = yb     + (size_t)NTOK * 1024;
  float* hid    = lastln + (size_t)32 * 512;

  // h = x @ inp_w^T + inp_b + pos   (K=142 -> scalar-guarded path)
  gemm_nt<<<dim3(50, 8), 64, 0, stream>>>(x, inp_w, h, NTOK, 512, 142,
                                          inp_b, pos, 1);

  for (int i = 0; i < 6; ++i) {
    ln_kernel<<<NTOK, 256, 0, stream>>>(h, hn, norm_g + (size_t)i * 512,
                                        norm_b + (size_t)i * 512, 512);
    gemm_nt<<<dim3(50, 32), 64, 0, stream>>>(hn, in_w + (size_t)i * 2048 * 512,
                                             xz, NTOK, 2048, 512,
                                             nullptr, nullptr, 0);
    conv_kernel<<<12800, 256, 0, stream>>>(xz, conv_w + (size_t)i * 1024 * 4,
                                           conv_b + (size_t)i * 1024, xc);
    xproj_kernel<<<800, 256, 0, stream>>>(xc, xproj_w + (size_t)i * 64 * 1024, xd);
    dt_kernel<<<12800, 256, 0, stream>>>(xd, dt_w + (size_t)i * 1024 * 32,
                                         dt_b + (size_t)i * 1024, dtb);
    scan_kernel<<<512, 64, 0, stream>>>(dtb, xc, xz, xd,
                                        A_log + (size_t)i * 1024 * 16,
                                        Dp + (size_t)i * 1024, yb);
    gemm_nt<<<dim3(50, 8), 64, 0, stream>>>(yb, out_w + (size_t)i * 512 * 1024,
                                            h, NTOK, 512, 1024,
                                            nullptr, nullptr, 2);
  }

  // final LN on last-token rows only, then 2-layer head
  ln_kernel<<<32, 256, 0, stream>>>(h + (size_t)(LSEQ - 1) * 512, lastln,
                                    lnf_g, lnf_b, (long)LSEQ * 512);
  head1<<<64, 256, 0, stream>>>(lastln, op1_w, op1_b, hid);
  head2<<<16, 256, 0, stream>>>(hid, op2_w, op2_b, out);
}

// Round 2
// 1558.086 us; speedup vs baseline: 2.1006x; 2.1006x over previous
//
#include <hip/hip_runtime.h>
#include <cmath>

// Model dims (fixed)
#define LSEQ 100
#define NTOK 3200   // B*L = 32*100

typedef __attribute__((ext_vector_type(8))) short bf16x8;   // 8 bf16 (4 VGPRs)
typedef __attribute__((ext_vector_type(4))) float f32x4;

__device__ inline unsigned short f2bf(float f) {
  union { float f; unsigned u; } v; v.f = f;
  unsigned r = v.u + 0x7FFF + ((v.u >> 16) & 1);   // round-nearest-even
  return (unsigned short)(r >> 16);
}

__device__ inline void async_ld16(const unsigned short* g, unsigned short* l) {
  __builtin_amdgcn_global_load_lds(
      (const __attribute__((address_space(1))) unsigned int*)g,
      (__attribute__((address_space(3))) unsigned int*)l,
      16, 0, 0);
}

// ---------------------------------------------------------------------------
// bf16 MFMA GEMM: C[M,N] (+)= A[M,K] @ W[N,K]^T, fp32 accumulate.
// 128x128 tile, BK=32, 256 thr (4 waves, 2x2 of 64x64), 16x16x32 MFMA.
// Requires M%128==0, N%128==0, K%32==0, A/W 16B-aligned.
// mode 0: C = acc ; mode 1: C += acc (residual accumulate)
// ---------------------------------------------------------------------------
__global__ __launch_bounds__(256)
void gemm_bf16(const unsigned short* __restrict__ A,
               const unsigned short* __restrict__ Wt,
               float* __restrict__ C, int M, int N, int K, int mode) {
  __shared__ unsigned short As[128 * 32];
  __shared__ unsigned short Bs[128 * 32];
  const int tid = threadIdx.x;
  const int lane = tid & 63, w = tid >> 6;
  const int row0 = blockIdx.x * 128, col0 = blockIdx.y * 128;

  f32x4 acc[4][4];
#pragma unroll
  for (int i = 0; i < 4; ++i)
#pragma unroll
    for (int j = 0; j < 4; ++j) acc[i][j] = (f32x4){0.f, 0.f, 0.f, 0.f};

  // staging: chunk c = tid + issue*256 covers tile row r=c>>2, k-chunk (c&3)*8
  const unsigned short* gA = A  + (size_t)(row0 + (tid >> 2)) * K + (tid & 3) * 8;
  const unsigned short* gB = Wt + (size_t)(col0 + (tid >> 2)) * K + (tid & 3) * 8;
  const size_t stride64 = (size_t)64 * K;
  unsigned short* lA = As + w * 512;   // wave-uniform LDS base (+ lane*16B by HW)
  unsigned short* lB = Bs + w * 512;

  const int mw = (w & 1) * 64, nw = (w >> 1) * 64;
  const int frow = lane & 15, fk = (lane >> 4) * 8;

  for (int k0 = 0; k0 < K; k0 += 32) {
    async_ld16(gA, lA);
    async_ld16(gA + stride64, lA + 2048);
    async_ld16(gB, lB);
    async_ld16(gB + stride64, lB + 2048);
    gA += 32; gB += 32;
    __syncthreads();   // drains vmcnt before barrier

    bf16x8 af[4], bf[4];
#pragma unroll
    for (int i = 0; i < 4; ++i)
      af[i] = *(const bf16x8*)&As[(mw + i * 16 + frow) * 32 + fk];
#pragma unroll
    for (int j = 0; j < 4; ++j)
      bf[j] = *(const bf16x8*)&Bs[(nw + j * 16 + frow) * 32 + fk];
#pragma unroll
    for (int i = 0; i < 4; ++i)
#pragma unroll
      for (int j = 0; j < 4; ++j)
        acc[i][j] = __builtin_amdgcn_mfma_f32_16x16x32_bf16(af[i], bf[j], acc[i][j], 0, 0, 0);
    __syncthreads();
  }

  // C/D layout: col = lane&15, row = (lane>>4)*4 + reg   [verified m89/m91]
  const int ccol = lane & 15, rq = (lane >> 4) * 4;
#pragma unroll
  for (int i = 0; i < 4; ++i) {
#pragma unroll
    for (int r = 0; r < 4; ++r) {
      const int row = row0 + mw + i * 16 + rq + r;
      float* crow = C + (size_t)row * N + col0 + nw + ccol;
#pragma unroll
      for (int j = 0; j < 4; ++j) {
        float v = acc[i][j][r];
        if (mode == 1) v += crow[j * 16];
        crow[j * 16] = v;
      }
    }
  }
}

// ---------------------------------------------------------------------------
// fp32 GEMM (kept for the one input projection, K=142): C = A@W^T (+bias+pos)
// ---------------------------------------------------------------------------
__global__ __launch_bounds__(64)
void gemm_nt(const float* __restrict__ A, const float* __restrict__ W,
             float* __restrict__ C, int M, int N, int K,
             const float* __restrict__ bias, const float* __restrict__ pos) {
  __shared__ float As[16][64];
  __shared__ float Bs[16][64];
  const int tid = threadIdx.x;
  const int row0 = blockIdx.x * 64, col0 = blockIdx.y * 64;
  float acc[8][8];
#pragma unroll
  for (int i = 0; i < 8; ++i)
#pragma unroll
    for (int j = 0; j < 8; ++j) acc[i][j] = 0.f;

  for (int k0 = 0; k0 < K; k0 += 16) {
#pragma unroll
    for (int c = 0; c < 4; ++c) {
      const int chunk = tid + c * 64;
      const int r  = chunk >> 2;
      const int kc = (chunk & 3) << 2;
      float a[4], wv[4];
#pragma unroll
      for (int jj = 0; jj < 4; ++jj) {
        int kk = k0 + kc + jj;
        a[jj]  = (kk < K) ? A[(size_t)(row0 + r) * K + kk] : 0.f;
        wv[jj] = (kk < K) ? W[(size_t)(col0 + r) * K + kk] : 0.f;
      }
#pragma unroll
      for (int jj = 0; jj < 4; ++jj) { As[kc + jj][r] = a[jj]; Bs[kc + jj][r] = wv[jj]; }
    }
    __syncthreads();
    const int tm = (tid & 7) * 8, tn = (tid >> 3) * 8;
#pragma unroll
    for (int k = 0; k < 16; ++k) {
      float av[8], bv[8];
      *(float4*)&av[0] = *(const float4*)&As[k][tm];
      *(float4*)&av[4] = *(const float4*)&As[k][tm + 4];
      *(float4*)&bv[0] = *(const float4*)&Bs[k][tn];
      *(float4*)&bv[4] = *(const float4*)&Bs[k][tn + 4];
#pragma unroll
      for (int i = 0; i < 8; ++i)
#pragma unroll
        for (int j = 0; j < 8; ++j)
          acc[i][j] += av[i] * bv[j];
    }
    __syncthreads();
  }
  const int tm = (tid & 7) * 8, tn = (tid >> 3) * 8;
#pragma unroll
  for (int i = 0; i < 8; ++i) {
    const int row = row0 + tm + i;
    float* crow = C + (size_t)row * N + (col0 + tn);
#pragma unroll
    for (int j = 0; j < 8; ++j) {
      float v = acc[i][j];
      if (bias) v += bias[col0 + tn + j];
      if (pos)  v += pos[(size_t)(row % LSEQ) * N + (col0 + tn + j)];
      crow[j] = v;
    }
  }
}

// ---------------------------------------------------------------------------
// fp32 -> bf16 conversion (n % 4 == 0)
// ---------------------------------------------------------------------------
__global__ __launch_bounds__(256)
void f2bf_kernel(const float* __restrict__ in, unsigned short* __restrict__ out, int n) {
  int i = (blockIdx.x * 256 + threadIdx.x) * 4;
  if (i >= n) return;
  float4 v = *(const float4*)(in + i);
  ushort4 o;
  o.x = f2bf(v.x); o.y = f2bf(v.y); o.z = f2bf(v.z); o.w = f2bf(v.w);
  *(ushort4*)(out + i) = o;
}

// ---------------------------------------------------------------------------
// LayerNorm over 512 cols. One block (256 thr) per row.
// Writes bf16 (obf) if non-null, else fp32 (o).
// ---------------------------------------------------------------------------
__global__ __launch_bounds__(256)
void ln_kernel(const float* __restrict__ x, float* __restrict__ o,
               unsigned short* __restrict__ obf,
               const float* __restrict__ g, const float* __restrict__ b,
               long rowStride) {
  const int row = blockIdx.x, tid = threadIdx.x;
  const float* xr = x + (size_t)row * rowStride;
  float v0 = xr[tid], v1 = xr[tid + 256];
  float s = v0 + v1, ss = v0 * v0 + v1 * v1;
#pragma unroll
  for (int off = 32; off > 0; off >>= 1) {
    s  += __shfl_down(s, off, 64);
    ss += __shfl_down(ss, off, 64);
  }
  __shared__ float rs[4], rss[4], mb[2];
  const int wid = tid >> 6;
  if ((tid & 63) == 0) { rs[wid] = s; rss[wid] = ss; }
  __syncthreads();
  if (tid == 0) {
    float S = rs[0] + rs[1] + rs[2] + rs[3];
    float SS = rss[0] + rss[1] + rss[2] + rss[3];
    float m = S * (1.f / 512.f);
    float var = SS * (1.f / 512.f) - m * m;
    mb[0] = m; mb[1] = rsqrtf(var + 1e-5f);
  }
  __syncthreads();
  const float m = mb[0], r = mb[1];
  float y0 = (v0 - m) * r * g[tid] + b[tid];
  float y1 = (v1 - m) * r * g[tid + 256] + b[tid + 256];
  if (obf) {
    obf[(size_t)row * 512 + tid]       = f2bf(y0);
    obf[(size_t)row * 512 + tid + 256] = f2bf(y1);
  } else {
    o[(size_t)row * 512 + tid]       = y0;
    o[(size_t)row * 512 + tid + 256] = y1;
  }
}

// ---------------------------------------------------------------------------
// Depthwise causal conv (K=4) + bias + SiLU.
// ---------------------------------------------------------------------------
__global__ __launch_bounds__(256)
void conv_kernel(const float* __restrict__ xz, const float* __restrict__ cw,
                 const float* __restrict__ cb, float* __restrict__ xc) {
  const int gid = blockIdx.x * 256 + threadIdx.x;
  const int d = gid & 1023;
  const int t = gid >> 10;
  const int b = t / LSEQ, l = t - b * LSEQ;
  const float4 w = *(const float4*)(cw + (size_t)d * 4);
  float acc = cb[d];
  const float* base = xz + (size_t)b * LSEQ * 2048 + d;
  const float wv[4] = {w.x, w.y, w.z, w.w};
#pragma unroll
  for (int k = 0; k < 4; ++k) {
    int ls = l - 3 + k;
    if (ls >= 0) acc += wv[k] * base[(size_t)ls * 2048];
  }
  xc[gid] = acc / (1.f + __expf(-acc));
}

// ---------------------------------------------------------------------------
// xd[t, 0:64] = xc[t, :] @ xproj_w[64,1024]^T.  4 tokens per block.
// ---------------------------------------------------------------------------
__global__ __launch_bounds__(256)
void xproj_kernel(const float* __restrict__ xc, const float* __restrict__ W,
                  float* __restrict__ xd) {
  __shared__ float sx[4][1024];
  __shared__ float red[4][4][64];
  const int tid = threadIdx.x;
  const size_t t0 = (size_t)blockIdx.x * 4;
  const float4* src = (const float4*)(xc + t0 * 1024);
  float4* dst = (float4*)sx;
#pragma unroll
  for (int i = 0; i < 4; ++i) dst[tid + i * 256] = src[tid + i * 256];
  __syncthreads();
  const int j = tid & 63, q = tid >> 6;
  const float* wr = W + (size_t)j * 1024 + q * 256;
  const float* s0 = &sx[0][q * 256];
  const float* s1 = &sx[1][q * 256];
  const float* s2 = &sx[2][q * 256];
  const float* s3 = &sx[3][q * 256];
  float p0 = 0, p1 = 0, p2 = 0, p3 = 0;
  for (int k = 0; k < 256; k += 4) {
    float4 wv = *(const float4*)(wr + k);
    p0 += wv.x * s0[k] + wv.y * s0[k + 1] + wv.z * s0[k + 2] + wv.w * s0[k + 3];
    p1 += wv.x * s1[k] + wv.y * s1[k + 1] + wv.z * s1[k + 2] + wv.w * s1[k + 3];
    p2 += wv.x * s2[k] + wv.y * s2[k + 1] + wv.z * s2[k + 2] + wv.w * s2[k + 3];
    p3 += wv.x * s3[k] + wv.y * s3[k + 1] + wv.z * s3[k + 2] + wv.w * s3[k + 3];
  }
  red[q][0][j] = p0; red[q][1][j] = p1; red[q][2][j] = p2; red[q][3][j] = p3;
  __syncthreads();
  const int tt = tid >> 6, jj = tid & 63;
  xd[(t0 + tt) * 64 + jj] =
      red[0][tt][jj] + red[1][tt][jj] + red[2][tt][jj] + red[3][tt][jj];
}

// ---------------------------------------------------------------------------
// dt[t,d] = softplus(xd[t,0:32] @ dt_w[d,:] + dt_b[d])
// ---------------------------------------------------------------------------
__global__ __launch_bounds__(256)
void dt_kernel(const float* __restrict__ xd, const float* __restrict__ dt_w,
               const float* __restrict__ dt_b, float* __restrict__ dt) {
  const int gid = blockIdx.x * 256 + threadIdx.x;
  const int t = gid >> 10, d = gid & 1023;
  const float* xr = xd + (size_t)t * 64;
  const float* wr = dt_w + (size_t)d * 32;
  float acc = dt_b[d];
#pragma unroll
  for (int r = 0; r < 32; r += 4) {
    float4 wv = *(const float4*)(wr + r);
    acc += wv.x * xr[r] + wv.y * xr[r + 1] + wv.z * xr[r + 2] + wv.w * xr[r + 3];
  }
  dt[gid] = (acc > 20.f) ? acc : log1pf(expf(acc));
}

// ---------------------------------------------------------------------------
// Selective scan. One thread per (b,d); 16 states in registers. bf16 output.
// ---------------------------------------------------------------------------
__global__ __launch_bounds__(64)
void scan_kernel(const float* __restrict__ dt, const float* __restrict__ xc,
                 const float* __restrict__ xz, const float* __restrict__ xd,
                 const float* __restrict__ A_log, const float* __restrict__ Dp,
                 unsigned short* __restrict__ y) {
  const int b = blockIdx.x >> 4;
  const int d = ((blockIdx.x & 15) << 6) + threadIdx.x;
  float Av[16], h[16];
#pragma unroll
  for (int n = 0; n < 16; ++n) {
    Av[n] = -__expf(A_log[(size_t)d * 16 + n]);
    h[n] = 0.f;
  }
  const float Dv = Dp[d];
  for (int t = 0; t < LSEQ; ++t) {
    const size_t tok = (size_t)b * LSEQ + t;
    const float dtv = dt[tok * 1024 + d];
    const float xcv = xc[tok * 1024 + d];
    const float zv  = xz[tok * 2048 + 1024 + d];
    const float dtxc = dtv * xcv;
    const float4* xr4 = (const float4*)(xd + tok * 64 + 32);
    float Bv[16], Cv[16];
    *(float4*)&Bv[0]  = xr4[0]; *(float4*)&Bv[4]  = xr4[1];
    *(float4*)&Bv[8]  = xr4[2]; *(float4*)&Bv[12] = xr4[3];
    *(float4*)&Cv[0]  = xr4[4]; *(float4*)&Cv[4]  = xr4[5];
    *(float4*)&Cv[8]  = xr4[6]; *(float4*)&Cv[12] = xr4[7];
    float yv = 0.f;
#pragma unroll
    for (int n = 0; n < 16; ++n) {
      float dA = __expf(dtv * Av[n]);
      h[n] = dA * h[n] + dtxc * Bv[n];
      yv += h[n] * Cv[n];
    }
    yv += Dv * xcv;
    yv *= zv / (1.f + __expf(-zv));
    y[tok * 1024 + d] = f2bf(yv);
  }
}

// ---------------------------------------------------------------------------
// Head
// ---------------------------------------------------------------------------
__global__ __launch_bounds__(256)
void head1(const float* __restrict__ a, const float* __restrict__ W,
           const float* __restrict__ bias, float* __restrict__ o) {
  const int gid = blockIdx.x * 256 + threadIdx.x;  // 32*512
  const int bb = gid >> 9, m = gid & 511;
  const float* ar = a + (size_t)bb * 512;
  const float* wr = W + (size_t)m * 512;
  float acc = bias[m];
  for (int k = 0; k < 512; k += 4) {
    float4 av = *(const float4*)(ar + k);
    float4 wv = *(const float4*)(wr + k);
    acc += av.x * wv.x + av.y * wv.y + av.z * wv.z + av.w * wv.w;
  }
  o[gid] = 0.5f * acc * (1.f + erff(acc * 0.7071067811865475f));
}

__global__ __launch_bounds__(256)
void head2(const float* __restrict__ hid, const float* __restrict__ W,
           const float* __restrict__ bias, float* __restrict__ o) {
  const int gid = blockIdx.x * 256 + threadIdx.x;  // 32*128
  const int bb = gid >> 7, m = gid & 127;
  const float* ar = hid + (size_t)bb * 512;
  const float* wr = W + (size_t)m * 512;
  float acc = bias[m];
  for (int k = 0; k < 512; k += 4) {
    float4 av = *(const float4*)(ar + k);
    float4 wv = *(const float4*)(wr + k);
    acc += av.x * wv.x + av.y * wv.y + av.z * wv.z + av.w * wv.w;
  }
  o[gid] = acc;
}

// ---------------------------------------------------------------------------
extern "C" void kernel_launch(void* const* d_in, const int* in_sizes, int n_in,
                              void* d_out, int out_size, void* d_ws, size_t ws_size,
                              hipStream_t stream) {
  const float* x      = (const float*)d_in[0];
  const float* inp_w  = (const float*)d_in[1];
  const float* inp_b  = (const float*)d_in[2];
  const float* pos    = (const float*)d_in[3];
  const float* norm_g = (const float*)d_in[4];
  const float* norm_b = (const float*)d_in[5];
  const float* in_w   = (const float*)d_in[6];
  const float* conv_w = (const float*)d_in[7];
  const float* conv_b = (const float*)d_in[8];
  const float* xproj_w= (const float*)d_in[9];
  const float* dt_w   = (const float*)d_in[10];
  const float* dt_b   = (const float*)d_in[11];
  const float* A_log  = (const float*)d_in[12];
  const float* Dp     = (const float*)d_in[13];
  const float* out_w  = (const float*)d_in[14];
  const float* lnf_g  = (const float*)d_in[15];
  const float* lnf_b  = (const float*)d_in[16];
  const float* op1_w  = (const float*)d_in[17];
  const float* op1_b  = (const float*)d_in[18];
  const float* op2_w  = (const float*)d_in[19];
  const float* op2_b  = (const float*)d_in[20];
  float* out = (float*)d_out;

  // workspace layout
  float* h      = (float*)d_ws;                       // NTOK*512
  float* xz     = h      + (size_t)NTOK * 512;        // NTOK*2048
  float* xc     = xz     + (size_t)NTOK * 2048;       // NTOK*1024
  float* xd     = xc     + (size_t)NTOK * 1024;       // NTOK*64
  float* dtb    = xd     + (size_t)NTOK * 64;         // NTOK*1024
  float* lastln = dtb    + (size_t)NTOK * 1024;       // 32*512
  float* hid    = lastln + (size_t)32 * 512;          // 32*512
  unsigned short* hn_bf  = (unsigned short*)(hid + (size_t)32 * 512);     // NTOK*512
  unsigned short* yb_bf  = hn_bf + (size_t)NTOK * 512;                    // NTOK*1024
  unsigned short* win_bf = yb_bf + (size_t)NTOK * 1024;                   // 2048*512
  unsigned short* wout_bf= win_bf + (size_t)2048 * 512;                   // 512*1024

  // h = x @ inp_w^T + inp_b + pos   (K=142 fp32 path, runs once)
  gemm_nt<<<dim3(50, 8), 64, 0, stream>>>(x, inp_w, h, NTOK, 512, 142, inp_b, pos);

  for (int i = 0; i < 6; ++i) {
    // convert this layer's GEMM weights to bf16
    f2bf_kernel<<<1024, 256, 0, stream>>>(in_w + (size_t)i * 2048 * 512, win_bf, 2048 * 512);
    f2bf_kernel<<<512, 256, 0, stream>>>(out_w + (size_t)i * 512 * 1024, wout_bf, 512 * 1024);

    ln_kernel<<<NTOK, 256, 0, stream>>>(h, nullptr, hn_bf,
                                        norm_g + (size_t)i * 512,
                                        norm_b + (size_t)i * 512, 512);
    gemm_bf16<<<dim3(25, 16), 256, 0, stream>>>(hn_bf, win_bf, xz,
                                                NTOK, 2048, 512, 0);
    conv_kernel<<<12800, 256, 0, stream>>>(xz, conv_w + (size_t)i * 1024 * 4,
                                           conv_b + (size_t)i * 1024, xc);
    xproj_kernel<<<800, 256, 0, stream>>>(xc, xproj_w + (size_t)i * 64 * 1024, xd);
    dt_kernel<<<12800, 256, 0, stream>>>(xd, dt_w + (size_t)i * 1024 * 32,
                                         dt_b + (size_t)i * 1024, dtb);
    scan_kernel<<<512, 64, 0, stream>>>(dtb, xc, xz, xd,
                                        A_log + (size_t)i * 1024 * 16,
                                        Dp + (size_t)i * 1024, yb_bf);
    gemm_bf16<<<dim3(25, 4), 256, 0, stream>>>(yb_bf, wout_bf, h,
                                               NTOK, 512, 1024, 1);
  }

  ln_kernel<<<32, 256, 0, stream>>>(h + (size_t)(LSEQ - 1) * 512, lastln, nullptr,
                                    lnf_g, lnf_b, (long)LSEQ * 512);
  head1<<<64, 256, 0, stream>>>(lastln, op1_w, op1_b, hid);
  head2<<<16, 256, 0, stream>>>(hid, op2_w, op2_b, out);
}

// Round 3
// 1208.897 us; speedup vs baseline: 2.7073x; 1.2888x over previous
//
#include <hip/hip_runtime.h>
#include <cmath>

// Model dims (fixed)
#define LSEQ 100
#define NTOK 3200   // B*L = 32*100

typedef __attribute__((ext_vector_type(8))) short bf16x8;   // 8 bf16 (4 VGPRs)
typedef __attribute__((ext_vector_type(4))) float f32x4;

__device__ inline unsigned short f2bf(float f) {
  union { float f; unsigned u; } v; v.f = f;
  unsigned r = v.u + 0x7FFF + ((v.u >> 16) & 1);   // round-nearest-even
  return (unsigned short)(r >> 16);
}

__device__ inline float softplus_fast(float x) {
  // log1p(exp(x)); for x>8, log1p(e^x)-x = e^-x < 3.4e-4 and only scales
  // already-negligible dA terms.
  return (x > 8.f) ? x : __logf(1.f + __expf(x));
}

__device__ inline void async_ld16(const unsigned short* g, unsigned short* l) {
  __builtin_amdgcn_global_load_lds(
      (const __attribute__((address_space(1))) unsigned int*)g,
      (__attribute__((address_space(3))) unsigned int*)l,
      16, 0, 0);
}

// ---------------------------------------------------------------------------
// bf16 MFMA GEMM: C[M,N] (+)= A[M,K] @ W[N,K]^T, fp32 accumulate.
// 128x128 tile, BK=32, 256 thr (4 waves, 2x2 of 64x64), 16x16x32 MFMA.
// mode 0: C = acc ; mode 1: C += acc (residual accumulate)
// ---------------------------------------------------------------------------
__global__ __launch_bounds__(256)
void gemm_bf16(const unsigned short* __restrict__ A,
               const unsigned short* __restrict__ Wt,
               float* __restrict__ C, int M, int N, int K, int mode) {
  __shared__ unsigned short As[128 * 32];
  __shared__ unsigned short Bs[128 * 32];
  const int tid = threadIdx.x;
  const int lane = tid & 63, w = tid >> 6;
  const int row0 = blockIdx.x * 128, col0 = blockIdx.y * 128;

  f32x4 acc[4][4];
#pragma unroll
  for (int i = 0; i < 4; ++i)
#pragma unroll
    for (int j = 0; j < 4; ++j) acc[i][j] = (f32x4){0.f, 0.f, 0.f, 0.f};

  const unsigned short* gA = A  + (size_t)(row0 + (tid >> 2)) * K + (tid & 3) * 8;
  const unsigned short* gB = Wt + (size_t)(col0 + (tid >> 2)) * K + (tid & 3) * 8;
  const size_t stride64 = (size_t)64 * K;
  unsigned short* lA = As + w * 512;
  unsigned short* lB = Bs + w * 512;

  const int mw = (w & 1) * 64, nw = (w >> 1) * 64;
  const int frow = lane & 15, fk = (lane >> 4) * 8;

  for (int k0 = 0; k0 < K; k0 += 32) {
    async_ld16(gA, lA);
    async_ld16(gA + stride64, lA + 2048);
    async_ld16(gB, lB);
    async_ld16(gB + stride64, lB + 2048);
    gA += 32; gB += 32;
    __syncthreads();

    bf16x8 af[4], bf[4];
#pragma unroll
    for (int i = 0; i < 4; ++i)
      af[i] = *(const bf16x8*)&As[(mw + i * 16 + frow) * 32 + fk];
#pragma unroll
    for (int j = 0; j < 4; ++j)
      bf[j] = *(const bf16x8*)&Bs[(nw + j * 16 + frow) * 32 + fk];
#pragma unroll
    for (int i = 0; i < 4; ++i)
#pragma unroll
      for (int j = 0; j < 4; ++j)
        acc[i][j] = __builtin_amdgcn_mfma_f32_16x16x32_bf16(af[i], bf[j], acc[i][j], 0, 0, 0);
    __syncthreads();
  }

  const int ccol = lane & 15, rq = (lane >> 4) * 4;
#pragma unroll
  for (int i = 0; i < 4; ++i) {
#pragma unroll
    for (int r = 0; r < 4; ++r) {
      const int row = row0 + mw + i * 16 + rq + r;
      float* crow = C + (size_t)row * N + col0 + nw + ccol;
#pragma unroll
      for (int j = 0; j < 4; ++j) {
        float v = acc[i][j][r];
        if (mode == 1) v += crow[j * 16];
        crow[j * 16] = v;
      }
    }
  }
}

// ---------------------------------------------------------------------------
// fp32 GEMM (input projection, K=142): C = A@W^T + bias + pos
// ---------------------------------------------------------------------------
__global__ __launch_bounds__(64)
void gemm_nt(const float* __restrict__ A, const float* __restrict__ W,
             float* __restrict__ C, int M, int N, int K,
             const float* __restrict__ bias, const float* __restrict__ pos) {
  __shared__ float As[16][64];
  __shared__ float Bs[16][64];
  const int tid = threadIdx.x;
  const int row0 = blockIdx.x * 64, col0 = blockIdx.y * 64;
  float acc[8][8];
#pragma unroll
  for (int i = 0; i < 8; ++i)
#pragma unroll
    for (int j = 0; j < 8; ++j) acc[i][j] = 0.f;

  for (int k0 = 0; k0 < K; k0 += 16) {
#pragma unroll
    for (int c = 0; c < 4; ++c) {
      const int chunk = tid + c * 64;
      const int r  = chunk >> 2;
      const int kc = (chunk & 3) << 2;
      float a[4], wv[4];
#pragma unroll
      for (int jj = 0; jj < 4; ++jj) {
        int kk = k0 + kc + jj;
        a[jj]  = (kk < K) ? A[(size_t)(row0 + r) * K + kk] : 0.f;
        wv[jj] = (kk < K) ? W[(size_t)(col0 + r) * K + kk] : 0.f;
      }
#pragma unroll
      for (int jj = 0; jj < 4; ++jj) { As[kc + jj][r] = a[jj]; Bs[kc + jj][r] = wv[jj]; }
    }
    __syncthreads();
    const int tm = (tid & 7) * 8, tn = (tid >> 3) * 8;
#pragma unroll
    for (int k = 0; k < 16; ++k) {
      float av[8], bv[8];
      *(float4*)&av[0] = *(const float4*)&As[k][tm];
      *(float4*)&av[4] = *(const float4*)&As[k][tm + 4];
      *(float4*)&bv[0] = *(const float4*)&Bs[k][tn];
      *(float4*)&bv[4] = *(const float4*)&Bs[k][tn + 4];
#pragma unroll
      for (int i = 0; i < 8; ++i)
#pragma unroll
        for (int j = 0; j < 8; ++j)
          acc[i][j] += av[i] * bv[j];
    }
    __syncthreads();
  }
  const int tm = (tid & 7) * 8, tn = (tid >> 3) * 8;
#pragma unroll
  for (int i = 0; i < 8; ++i) {
    const int row = row0 + tm + i;
    float* crow = C + (size_t)row * N + (col0 + tn);
#pragma unroll
    for (int j = 0; j < 8; ++j) {
      float v = acc[i][j];
      if (bias) v += bias[col0 + tn + j];
      if (pos)  v += pos[(size_t)(row % LSEQ) * N + (col0 + tn + j)];
      crow[j] = v;
    }
  }
}

// ---------------------------------------------------------------------------
// fp32 -> bf16 conversion
// ---------------------------------------------------------------------------
__global__ __launch_bounds__(256)
void f2bf_kernel(const float* __restrict__ in, unsigned short* __restrict__ out, int n) {
  int i = (blockIdx.x * 256 + threadIdx.x) * 4;
  if (i >= n) return;
  float4 v = *(const float4*)(in + i);
  ushort4 o;
  o.x = f2bf(v.x); o.y = f2bf(v.y); o.z = f2bf(v.z); o.w = f2bf(v.w);
  *(ushort4*)(out + i) = o;
}

// ---------------------------------------------------------------------------
// LayerNorm over 512 cols. bf16 out (obf) if non-null else fp32 (o).
// ---------------------------------------------------------------------------
__global__ __launch_bounds__(256)
void ln_kernel(const float* __restrict__ x, float* __restrict__ o,
               unsigned short* __restrict__ obf,
               const float* __restrict__ g, const float* __restrict__ b,
               long rowStride) {
  const int row = blockIdx.x, tid = threadIdx.x;
  const float* xr = x + (size_t)row * rowStride;
  float v0 = xr[tid], v1 = xr[tid + 256];
  float s = v0 + v1, ss = v0 * v0 + v1 * v1;
#pragma unroll
  for (int off = 32; off > 0; off >>= 1) {
    s  += __shfl_down(s, off, 64);
    ss += __shfl_down(ss, off, 64);
  }
  __shared__ float rs[4], rss[4], mb[2];
  const int wid = tid >> 6;
  if ((tid & 63) == 0) { rs[wid] = s; rss[wid] = ss; }
  __syncthreads();
  if (tid == 0) {
    float S = rs[0] + rs[1] + rs[2] + rs[3];
    float SS = rss[0] + rss[1] + rss[2] + rss[3];
    float m = S * (1.f / 512.f);
    float var = SS * (1.f / 512.f) - m * m;
    mb[0] = m; mb[1] = rsqrtf(var + 1e-5f);
  }
  __syncthreads();
  const float m = mb[0], r = mb[1];
  float y0 = (v0 - m) * r * g[tid] + b[tid];
  float y1 = (v1 - m) * r * g[tid + 256] + b[tid + 256];
  if (obf) {
    obf[(size_t)row * 512 + tid]       = f2bf(y0);
    obf[(size_t)row * 512 + tid + 256] = f2bf(y1);
  } else {
    o[(size_t)row * 512 + tid]       = y0;
    o[(size_t)row * 512 + tid + 256] = y1;
  }
}

// ---------------------------------------------------------------------------
// Fused conv(K=4,silu) + xproj(64x1024) + dt-proj(softplus).
// One block = 4 tokens (never crosses a batch boundary: 100%4==0).
// Phase 1: conv -> sxc (LDS) + xc (global, for scan)
// Phase 2: xd = sxc @ xproj_w^T -> sxd (LDS) + xd (global, B/C for scan)
// Phase 3: dt = softplus(sxd[:, :32] @ dt_w^T + dt_b), dt_w staged in LDS
//          in 256-row chunks (coalesced load, pad-33 conflict-free reads).
// ---------------------------------------------------------------------------
__global__ __launch_bounds__(256)
void mid_kernel(const float* __restrict__ xz,
                const float* __restrict__ xpw,   // [64,1024]
                const float* __restrict__ dtw,   // [1024,32]
                const float* __restrict__ dtb_p, // [1024]
                const float* __restrict__ cw,    // [1024,4]
                const float* __restrict__ cb,    // [1024]
                float* __restrict__ xcg, float* __restrict__ xdg,
                float* __restrict__ dtg) {
  __shared__ float sxc[4][1024];     // 16 KB
  __shared__ float red[4][4][64];    // 4 KB
  __shared__ float sxd[4][64];       // 1 KB
  __shared__ float sdt[256 * 33];    // 33.8 KB
  const int tid = threadIdx.x;
  const int t0 = blockIdx.x * 4;
  const int b = t0 / LSEQ, l0 = t0 - b * LSEQ;

  // ---- phase 1: conv + silu ----
#pragma unroll
  for (int rep = 0; rep < 4; ++rep) {
    const int d = rep * 256 + tid;
    const float4 w4 = *(const float4*)(cw + (size_t)d * 4);
    const float cbv = cb[d];
    const float* base = xz + (size_t)b * LSEQ * 2048 + d;
    float v[7];
#pragma unroll
    for (int j = 0; j < 7; ++j) {
      int ls = l0 - 3 + j;
      v[j] = (ls >= 0) ? base[(size_t)ls * 2048] : 0.f;
    }
#pragma unroll
    for (int tt = 0; tt < 4; ++tt) {
      float a = cbv + w4.x * v[tt] + w4.y * v[tt + 1] + w4.z * v[tt + 2] + w4.w * v[tt + 3];
      a = a / (1.f + __expf(-a));
      sxc[tt][d] = a;
      xcg[(size_t)(t0 + tt) * 1024 + d] = a;
    }
  }
  __syncthreads();

  // ---- phase 2: xproj ----
  {
    const int j = tid & 63, q = tid >> 6;
    const float* wr = xpw + (size_t)j * 1024 + q * 256;
    const float* s0 = &sxc[0][q * 256];
    const float* s1 = &sxc[1][q * 256];
    const float* s2 = &sxc[2][q * 256];
    const float* s3 = &sxc[3][q * 256];
    float p0 = 0, p1 = 0, p2 = 0, p3 = 0;
    for (int k = 0; k < 256; k += 4) {
      float4 wv = *(const float4*)(wr + k);
      p0 += wv.x * s0[k] + wv.y * s0[k + 1] + wv.z * s0[k + 2] + wv.w * s0[k + 3];
      p1 += wv.x * s1[k] + wv.y * s1[k + 1] + wv.z * s1[k + 2] + wv.w * s1[k + 3];
      p2 += wv.x * s2[k] + wv.y * s2[k + 1] + wv.z * s2[k + 2] + wv.w * s2[k + 3];
      p3 += wv.x * s3[k] + wv.y * s3[k + 1] + wv.z * s3[k + 2] + wv.w * s3[k + 3];
    }
    red[q][0][j] = p0; red[q][1][j] = p1; red[q][2][j] = p2; red[q][3][j] = p3;
  }
  __syncthreads();
  {
    const int tt = tid >> 6, jj = tid & 63;
    float xv = red[0][tt][jj] + red[1][tt][jj] + red[2][tt][jj] + red[3][tt][jj];
    sxd[tt][jj] = xv;
    xdg[(size_t)(t0 + tt) * 64 + jj] = xv;
  }
  __syncthreads();

  // ---- phase 3: dt ----
  for (int c = 0; c < 4; ++c) {
#pragma unroll
    for (int i = 0; i < 8; ++i) {
      const int lin = i * 1024 + tid * 4;
      const int dr = lin >> 5, kk = lin & 31;
      float4 wv = *(const float4*)(dtw + c * 8192 + lin);
      sdt[dr * 33 + kk]     = wv.x;
      sdt[dr * 33 + kk + 1] = wv.y;
      sdt[dr * 33 + kk + 2] = wv.z;
      sdt[dr * 33 + kk + 3] = wv.w;
    }
    __syncthreads();
    const int d = c * 256 + tid;
    const float bias = dtb_p[d];
    const float* row = &sdt[tid * 33];
    float a0 = bias, a1 = bias, a2 = bias, a3 = bias;
#pragma unroll
    for (int k = 0; k < 32; ++k) {
      const float wk = row[k];
      a0 += sxd[0][k] * wk;
      a1 += sxd[1][k] * wk;
      a2 += sxd[2][k] * wk;
      a3 += sxd[3][k] * wk;
    }
    dtg[(size_t)(t0 + 0) * 1024 + d] = softplus_fast(a0);
    dtg[(size_t)(t0 + 1) * 1024 + d] = softplus_fast(a1);
    dtg[(size_t)(t0 + 2) * 1024 + d] = softplus_fast(a2);
    dtg[(size_t)(t0 + 3) * 1024 + d] = softplus_fast(a3);
    __syncthreads();
  }
}

// ---------------------------------------------------------------------------
// Selective scan, 4-way state split: thread = (b, d, n-quad), 4 states each.
// lanes: nq = lane&3, dl = lane>>2; y reduced via shfl_xor(1), shfl_xor(2).
// Grid: (16 dgroups, 32 batches) x 256 thr -> 2048 waves (2/SIMD).
// ---------------------------------------------------------------------------
__global__ __launch_bounds__(256)
void scan_kernel(const float* __restrict__ dtg, const float* __restrict__ xcg,
                 const float* __restrict__ xz, const float* __restrict__ xdg,
                 const float* __restrict__ A_log, const float* __restrict__ Dp,
                 unsigned short* __restrict__ y) {
  const int tid = threadIdx.x;
  const int lane = tid & 63, w = tid >> 6;
  const int nq = lane & 3, dl = lane >> 2;
  const int b = blockIdx.y;
  const int d = blockIdx.x * 64 + w * 16 + dl;

  float4 a4 = *(const float4*)(A_log + (size_t)d * 16 + nq * 4);
  float Av0 = -__expf(a4.x), Av1 = -__expf(a4.y), Av2 = -__expf(a4.z), Av3 = -__expf(a4.w);
  float h0 = 0.f, h1 = 0.f, h2 = 0.f, h3 = 0.f;
  const float Dv = Dp[d];

  const size_t tok0 = (size_t)b * LSEQ;
  // prefetch t=0
  float dt_n = dtg[tok0 * 1024 + d];
  float xc_n = xcg[tok0 * 1024 + d];
  float z_n  = xz[tok0 * 2048 + 1024 + d];
  float4 B_n = *(const float4*)(xdg + tok0 * 64 + 32 + nq * 4);
  float4 C_n = *(const float4*)(xdg + tok0 * 64 + 48 + nq * 4);

  for (int t = 0; t < LSEQ; ++t) {
    const float dtv = dt_n, xcv = xc_n, zv = z_n;
    const float4 Bv = B_n, Cv = C_n;
    const int tn = (t < LSEQ - 1) ? t + 1 : t;
    const size_t tk2 = tok0 + tn;
    dt_n = dtg[tk2 * 1024 + d];
    xc_n = xcg[tk2 * 1024 + d];
    z_n  = xz[tk2 * 2048 + 1024 + d];
    B_n = *(const float4*)(xdg + tk2 * 64 + 32 + nq * 4);
    C_n = *(const float4*)(xdg + tk2 * 64 + 48 + nq * 4);

    const float dtxc = dtv * xcv;
    h0 = __expf(dtv * Av0) * h0 + dtxc * Bv.x;
    float yp = h0 * Cv.x;
    h1 = __expf(dtv * Av1) * h1 + dtxc * Bv.y;
    yp += h1 * Cv.y;
    h2 = __expf(dtv * Av2) * h2 + dtxc * Bv.z;
    yp += h2 * Cv.z;
    h3 = __expf(dtv * Av3) * h3 + dtxc * Bv.w;
    yp += h3 * Cv.w;

    yp += __shfl_xor(yp, 1, 64);
    yp += __shfl_xor(yp, 2, 64);

    if (nq == 0) {
      float yv = (yp + Dv * xcv) * (zv / (1.f + __expf(-zv)));
      y[(tok0 + t) * 1024 + d] = f2bf(yv);
    }
  }
}

// ---------------------------------------------------------------------------
// Head
// ---------------------------------------------------------------------------
__global__ __launch_bounds__(256)
void head1(const float* __restrict__ a, const float* __restrict__ W,
           const float* __restrict__ bias, float* __restrict__ o) {
  const int gid = blockIdx.x * 256 + threadIdx.x;  // 32*512
  const int bb = gid >> 9, m = gid & 511;
  const float* ar = a + (size_t)bb * 512;
  const float* wr = W + (size_t)m * 512;
  float acc = bias[m];
  for (int k = 0; k < 512; k += 4) {
    float4 av = *(const float4*)(ar + k);
    float4 wv = *(const float4*)(wr + k);
    acc += av.x * wv.x + av.y * wv.y + av.z * wv.z + av.w * wv.w;
  }
  o[gid] = 0.5f * acc * (1.f + erff(acc * 0.7071067811865475f));
}

__global__ __launch_bounds__(256)
void head2(const float* __restrict__ hid, const float* __restrict__ W,
           const float* __restrict__ bias, float* __restrict__ o) {
  const int gid = blockIdx.x * 256 + threadIdx.x;  // 32*128
  const int bb = gid >> 7, m = gid & 127;
  const float* ar = hid + (size_t)bb * 512;
  const float* wr = W + (size_t)m * 512;
  float acc = bias[m];
  for (int k = 0; k < 512; k += 4) {
    float4 av = *(const float4*)(ar + k);
    float4 wv = *(const float4*)(wr + k);
    acc += av.x * wv.x + av.y * wv.y + av.z * wv.z + av.w * wv.w;
  }
  o[gid] = acc;
}

// ---------------------------------------------------------------------------
extern "C" void kernel_launch(void* const* d_in, const int* in_sizes, int n_in,
                              void* d_out, int out_size, void* d_ws, size_t ws_size,
                              hipStream_t stream) {
  const float* x      = (const float*)d_in[0];
  const float* inp_w  = (const float*)d_in[1];
  const float* inp_b  = (const float*)d_in[2];
  const float* pos    = (const float*)d_in[3];
  const float* norm_g = (const float*)d_in[4];
  const float* norm_b = (const float*)d_in[5];
  const float* in_w   = (const float*)d_in[6];
  const float* conv_w = (const float*)d_in[7];
  const float* conv_b = (const float*)d_in[8];
  const float* xproj_w= (const float*)d_in[9];
  const float* dt_w   = (const float*)d_in[10];
  const float* dt_b   = (const float*)d_in[11];
  const float* A_log  = (const float*)d_in[12];
  const float* Dp     = (const float*)d_in[13];
  const float* out_w  = (const float*)d_in[14];
  const float* lnf_g  = (const float*)d_in[15];
  const float* lnf_b  = (const float*)d_in[16];
  const float* op1_w  = (const float*)d_in[17];
  const float* op1_b  = (const float*)d_in[18];
  const float* op2_w  = (const float*)d_in[19];
  const float* op2_b  = (const float*)d_in[20];
  float* out = (float*)d_out;

  // workspace layout
  float* h      = (float*)d_ws;                       // NTOK*512
  float* xz     = h      + (size_t)NTOK * 512;        // NTOK*2048
  float* xc     = xz     + (size_t)NTOK * 2048;       // NTOK*1024
  float* xd     = xc     + (size_t)NTOK * 1024;       // NTOK*64
  float* dtb    = xd     + (size_t)NTOK * 64;         // NTOK*1024
  float* lastln = dtb    + (size_t)NTOK * 1024;       // 32*512
  float* hid    = lastln + (size_t)32 * 512;          // 32*512
  unsigned short* hn_bf  = (unsigned short*)(hid + (size_t)32 * 512);     // NTOK*512
  unsigned short* yb_bf  = hn_bf + (size_t)NTOK * 512;                    // NTOK*1024
  unsigned short* win_bf = yb_bf + (size_t)NTOK * 1024;                   // 2048*512
  unsigned short* wout_bf= win_bf + (size_t)2048 * 512;                   // 512*1024

  // h = x @ inp_w^T + inp_b + pos   (K=142 fp32 path, runs once)
  gemm_nt<<<dim3(50, 8), 64, 0, stream>>>(x, inp_w, h, NTOK, 512, 142, inp_b, pos);

  for (int i = 0; i < 6; ++i) {
    f2bf_kernel<<<1024, 256, 0, stream>>>(in_w + (size_t)i * 2048 * 512, win_bf, 2048 * 512);
    f2bf_kernel<<<512, 256, 0, stream>>>(out_w + (size_t)i * 512 * 1024, wout_bf, 512 * 1024);

    ln_kernel<<<NTOK, 256, 0, stream>>>(h, nullptr, hn_bf,
                                        norm_g + (size_t)i * 512,
                                        norm_b + (size_t)i * 512, 512);
    gemm_bf16<<<dim3(25, 16), 256, 0, stream>>>(hn_bf, win_bf, xz,
                                                NTOK, 2048, 512, 0);
    mid_kernel<<<800, 256, 0, stream>>>(xz,
                                        xproj_w + (size_t)i * 64 * 1024,
                                        dt_w + (size_t)i * 1024 * 32,
                                        dt_b + (size_t)i * 1024,
                                        conv_w + (size_t)i * 1024 * 4,
                                        conv_b + (size_t)i * 1024,
                                        xc, xd, dtb);
    scan_kernel<<<dim3(16, 32), 256, 0, stream>>>(dtb, xc, xz, xd,
                                                  A_log + (size_t)i * 1024 * 16,
                                                  Dp + (size_t)i * 1024, yb_bf);
    gemm_bf16<<<dim3(25, 4), 256, 0, stream>>>(yb_bf, wout_bf, h,
                                               NTOK, 512, 1024, 1);
  }

  ln_kernel<<<32, 256, 0, stream>>>(h + (size_t)(LSEQ - 1) * 512, lastln, nullptr,
                                    lnf_g, lnf_b, (long)LSEQ * 512);
  head1<<<64, 256, 0, stream>>>(lastln, op1_w, op1_b, hid);
  head2<<<16, 256, 0, stream>>>(hid, op2_w, op2_b, out);
}

// Round 4
// 1203.882 us; speedup vs baseline: 2.7186x; 1.0042x over previous
//
#include <hip/hip_runtime.h>
#include <cmath>

// Model dims (fixed)
#define LSEQ 100
#define NTOK 3200   // B*L = 32*100

typedef __attribute__((ext_vector_type(8))) short bf16x8;   // 8 bf16 (4 VGPRs)
typedef __attribute__((ext_vector_type(4))) float f32x4;

__device__ inline unsigned short f2bf(float f) {
  union { float f; unsigned u; } v; v.f = f;
  unsigned r = v.u + 0x7FFF + ((v.u >> 16) & 1);   // round-nearest-even
  return (unsigned short)(r >> 16);
}

__device__ inline float softplus_fast(float x) {
  return (x > 8.f) ? x : __logf(1.f + __expf(x));
}

__device__ inline void async_ld16(const unsigned short* g, unsigned short* l) {
  __builtin_amdgcn_global_load_lds(
      (const __attribute__((address_space(1))) unsigned int*)g,
      (__attribute__((address_space(3))) unsigned int*)l,
      16, 0, 0);
}

// ---------------------------------------------------------------------------
// bf16 MFMA GEMM: C[M,N] (+)= A[M,K] @ W[N,K]^T, fp32 accumulate.
// 128x128 tile, BK=32, 256 thr (4 waves, 2x2 of 64x64), 16x16x32 MFMA.
// mode 0: C = acc ; mode 1: C += acc (residual accumulate)
// ---------------------------------------------------------------------------
__global__ __launch_bounds__(256)
void gemm_bf16(const unsigned short* __restrict__ A,
               const unsigned short* __restrict__ Wt,
               float* __restrict__ C, int M, int N, int K, int mode) {
  __shared__ unsigned short As[128 * 32];
  __shared__ unsigned short Bs[128 * 32];
  const int tid = threadIdx.x;
  const int lane = tid & 63, w = tid >> 6;
  const int row0 = blockIdx.x * 128, col0 = blockIdx.y * 128;

  f32x4 acc[4][4];
#pragma unroll
  for (int i = 0; i < 4; ++i)
#pragma unroll
    for (int j = 0; j < 4; ++j) acc[i][j] = (f32x4){0.f, 0.f, 0.f, 0.f};

  const unsigned short* gA = A  + (size_t)(row0 + (tid >> 2)) * K + (tid & 3) * 8;
  const unsigned short* gB = Wt + (size_t)(col0 + (tid >> 2)) * K + (tid & 3) * 8;
  const size_t stride64 = (size_t)64 * K;
  unsigned short* lA = As + w * 512;
  unsigned short* lB = Bs + w * 512;

  const int mw = (w & 1) * 64, nw = (w >> 1) * 64;
  const int frow = lane & 15, fk = (lane >> 4) * 8;

  for (int k0 = 0; k0 < K; k0 += 32) {
    async_ld16(gA, lA);
    async_ld16(gA + stride64, lA + 2048);
    async_ld16(gB, lB);
    async_ld16(gB + stride64, lB + 2048);
    gA += 32; gB += 32;
    __syncthreads();

    bf16x8 af[4], bf[4];
#pragma unroll
    for (int i = 0; i < 4; ++i)
      af[i] = *(const bf16x8*)&As[(mw + i * 16 + frow) * 32 + fk];
#pragma unroll
    for (int j = 0; j < 4; ++j)
      bf[j] = *(const bf16x8*)&Bs[(nw + j * 16 + frow) * 32 + fk];
#pragma unroll
    for (int i = 0; i < 4; ++i)
#pragma unroll
      for (int j = 0; j < 4; ++j)
        acc[i][j] = __builtin_amdgcn_mfma_f32_16x16x32_bf16(af[i], bf[j], acc[i][j], 0, 0, 0);
    __syncthreads();
  }

  const int ccol = lane & 15, rq = (lane >> 4) * 4;
#pragma unroll
  for (int i = 0; i < 4; ++i) {
#pragma unroll
    for (int r = 0; r < 4; ++r) {
      const int row = row0 + mw + i * 16 + rq + r;
      float* crow = C + (size_t)row * N + col0 + nw + ccol;
#pragma unroll
      for (int j = 0; j < 4; ++j) {
        float v = acc[i][j][r];
        if (mode == 1) v += crow[j * 16];
        crow[j * 16] = v;
      }
    }
  }
}

// ---------------------------------------------------------------------------
// fp32 GEMM (input projection, K=142): C = A@W^T + bias + pos
// ---------------------------------------------------------------------------
__global__ __launch_bounds__(64)
void gemm_nt(const float* __restrict__ A, const float* __restrict__ W,
             float* __restrict__ C, int M, int N, int K,
             const float* __restrict__ bias, const float* __restrict__ pos) {
  __shared__ float As[16][64];
  __shared__ float Bs[16][64];
  const int tid = threadIdx.x;
  const int row0 = blockIdx.x * 64, col0 = blockIdx.y * 64;
  float acc[8][8];
#pragma unroll
  for (int i = 0; i < 8; ++i)
#pragma unroll
    for (int j = 0; j < 8; ++j) acc[i][j] = 0.f;

  for (int k0 = 0; k0 < K; k0 += 16) {
#pragma unroll
    for (int c = 0; c < 4; ++c) {
      const int chunk = tid + c * 64;
      const int r  = chunk >> 2;
      const int kc = (chunk & 3) << 2;
      float a[4], wv[4];
#pragma unroll
      for (int jj = 0; jj < 4; ++jj) {
        int kk = k0 + kc + jj;
        a[jj]  = (kk < K) ? A[(size_t)(row0 + r) * K + kk] : 0.f;
        wv[jj] = (kk < K) ? W[(size_t)(col0 + r) * K + kk] : 0.f;
      }
#pragma unroll
      for (int jj = 0; jj < 4; ++jj) { As[kc + jj][r] = a[jj]; Bs[kc + jj][r] = wv[jj]; }
    }
    __syncthreads();
    const int tm = (tid & 7) * 8, tn = (tid >> 3) * 8;
#pragma unroll
    for (int k = 0; k < 16; ++k) {
      float av[8], bv[8];
      *(float4*)&av[0] = *(const float4*)&As[k][tm];
      *(float4*)&av[4] = *(const float4*)&As[k][tm + 4];
      *(float4*)&bv[0] = *(const float4*)&Bs[k][tn];
      *(float4*)&bv[4] = *(const float4*)&Bs[k][tn + 4];
#pragma unroll
      for (int i = 0; i < 8; ++i)
#pragma unroll
        for (int j = 0; j < 8; ++j)
          acc[i][j] += av[i] * bv[j];
    }
    __syncthreads();
  }
  const int tm = (tid & 7) * 8, tn = (tid >> 3) * 8;
#pragma unroll
  for (int i = 0; i < 8; ++i) {
    const int row = row0 + tm + i;
    float* crow = C + (size_t)row * N + (col0 + tn);
#pragma unroll
    for (int j = 0; j < 8; ++j) {
      float v = acc[i][j];
      if (bias) v += bias[col0 + tn + j];
      if (pos)  v += pos[(size_t)(row % LSEQ) * N + (col0 + tn + j)];
      crow[j] = v;
    }
  }
}

// ---------------------------------------------------------------------------
// fp32 -> bf16 conversion
// ---------------------------------------------------------------------------
__global__ __launch_bounds__(256)
void f2bf_kernel(const float* __restrict__ in, unsigned short* __restrict__ out, int n) {
  int i = (blockIdx.x * 256 + threadIdx.x) * 4;
  if (i >= n) return;
  float4 v = *(const float4*)(in + i);
  ushort4 o;
  o.x = f2bf(v.x); o.y = f2bf(v.y); o.z = f2bf(v.z); o.w = f2bf(v.w);
  *(ushort4*)(out + i) = o;
}

// ---------------------------------------------------------------------------
// Transpose xproj_w: in [6][64][1024] -> out [6][1024][64]. 64x64 LDS tiles.
// grid (16, 6)
// ---------------------------------------------------------------------------
__global__ __launch_bounds__(256)
void xpose_xpw(const float* __restrict__ in, float* __restrict__ out) {
  __shared__ float t[64][65];
  const int layer = blockIdx.y, kt = blockIdx.x;
  const float* src = in + (size_t)layer * 65536 + kt * 64;
  float* dst = out + (size_t)layer * 65536 + (size_t)kt * 64 * 64;
  const int tid = threadIdx.x, jr = tid >> 6, kk = tid & 63;
#pragma unroll
  for (int rr = 0; rr < 64; rr += 4)
    t[rr + jr][kk] = src[(size_t)(rr + jr) * 1024 + kk];
  __syncthreads();
#pragma unroll
  for (int rr = 0; rr < 64; rr += 4) {
    const int kl = rr + jr;
    dst[(size_t)kl * 64 + kk] = t[kk][kl];
  }
}

// ---------------------------------------------------------------------------
// Transpose dt_w: in [6][1024][32] -> out [6][32][1024]. Naive (tiny).
// grid 768
// ---------------------------------------------------------------------------
__global__ __launch_bounds__(256)
void xpose_dtw(const float* __restrict__ in, float* __restrict__ out) {
  const int id = blockIdx.x * 256 + threadIdx.x;   // 6*32*1024
  const int i = id >> 15, r = id & 32767;
  const int k = r >> 10, d = r & 1023;
  out[id] = in[(size_t)i * 32768 + d * 32 + k];
}

// ---------------------------------------------------------------------------
// LayerNorm over 512 cols. bf16 out (obf) if non-null else fp32 (o).
// ---------------------------------------------------------------------------
__global__ __launch_bounds__(256)
void ln_kernel(const float* __restrict__ x, float* __restrict__ o,
               unsigned short* __restrict__ obf,
               const float* __restrict__ g, const float* __restrict__ b,
               long rowStride) {
  const int row = blockIdx.x, tid = threadIdx.x;
  const float* xr = x + (size_t)row * rowStride;
  float v0 = xr[tid], v1 = xr[tid + 256];
  float s = v0 + v1, ss = v0 * v0 + v1 * v1;
#pragma unroll
  for (int off = 32; off > 0; off >>= 1) {
    s  += __shfl_down(s, off, 64);
    ss += __shfl_down(ss, off, 64);
  }
  __shared__ float rs[4], rss[4], mb[2];
  const int wid = tid >> 6;
  if ((tid & 63) == 0) { rs[wid] = s; rss[wid] = ss; }
  __syncthreads();
  if (tid == 0) {
    float S = rs[0] + rs[1] + rs[2] + rs[3];
    float SS = rss[0] + rss[1] + rss[2] + rss[3];
    float m = S * (1.f / 512.f);
    float var = SS * (1.f / 512.f) - m * m;
    mb[0] = m; mb[1] = rsqrtf(var + 1e-5f);
  }
  __syncthreads();
  const float m = mb[0], r = mb[1];
  float y0 = (v0 - m) * r * g[tid] + b[tid];
  float y1 = (v1 - m) * r * g[tid + 256] + b[tid + 256];
  if (obf) {
    obf[(size_t)row * 512 + tid]       = f2bf(y0);
    obf[(size_t)row * 512 + tid + 256] = f2bf(y1);
  } else {
    o[(size_t)row * 512 + tid]       = y0;
    o[(size_t)row * 512 + tid + 256] = y1;
  }
}

// ---------------------------------------------------------------------------
// Fused conv(K=4,silu) + xproj + dt-proj. 4 tokens/block, 256 thr.
// Weights pre-transposed: xpwT [1024][64], dtwT [32][1024] -> all global
// weight reads coalesced; no dt_w LDS staging. LDS = 21 KB.
// ---------------------------------------------------------------------------
__global__ __launch_bounds__(256)
void mid_kernel(const float* __restrict__ xz,
                const float* __restrict__ xpwT,  // [1024][64]
                const float* __restrict__ dtwT,  // [32][1024]
                const float* __restrict__ dtb_p, // [1024]
                const float* __restrict__ cw,    // [1024][4]
                const float* __restrict__ cb,    // [1024]
                float* __restrict__ xcg, float* __restrict__ xdg,
                float* __restrict__ dtg) {
  __shared__ float sxc[4][1024];     // 16 KB
  __shared__ float red[4][4][64];    // 4 KB
  __shared__ float sxd[4][64];       // 1 KB
  const int tid = threadIdx.x;
  const int t0 = blockIdx.x * 4;
  const int b = t0 / LSEQ, l0 = t0 - b * LSEQ;

  // ---- phase 1: conv + silu ----
#pragma unroll
  for (int rep = 0; rep < 4; ++rep) {
    const int d = rep * 256 + tid;
    const float4 w4 = *(const float4*)(cw + (size_t)d * 4);
    const float cbv = cb[d];
    const float* base = xz + (size_t)b * LSEQ * 2048 + d;
    float v[7];
#pragma unroll
    for (int j = 0; j < 7; ++j) {
      int ls = l0 - 3 + j;
      v[j] = (ls >= 0) ? base[(size_t)ls * 2048] : 0.f;
    }
#pragma unroll
    for (int tt = 0; tt < 4; ++tt) {
      float a = cbv + w4.x * v[tt] + w4.y * v[tt + 1] + w4.z * v[tt + 2] + w4.w * v[tt + 3];
      a = a / (1.f + __expf(-a));
      sxc[tt][d] = a;
      xcg[(size_t)(t0 + tt) * 1024 + d] = a;
    }
  }
  __syncthreads();

  // ---- phase 2: xproj (coalesced weight reads, float4 LDS broadcasts) ----
  {
    const int j = tid & 63, q = tid >> 6;
    const float* wq = xpwT + (size_t)q * 256 * 64 + j;
    float p0 = 0, p1 = 0, p2 = 0, p3 = 0;
    for (int k2 = 0; k2 < 256; k2 += 4) {
      const int k = q * 256 + k2;
      float4 s0 = *(const float4*)&sxc[0][k];
      float4 s1 = *(const float4*)&sxc[1][k];
      float4 s2 = *(const float4*)&sxc[2][k];
      float4 s3 = *(const float4*)&sxc[3][k];
      float w0 = wq[(size_t)k2 * 64];
      float w1 = wq[(size_t)(k2 + 1) * 64];
      float w2 = wq[(size_t)(k2 + 2) * 64];
      float w3 = wq[(size_t)(k2 + 3) * 64];
      p0 += w0 * s0.x + w1 * s0.y + w2 * s0.z + w3 * s0.w;
      p1 += w0 * s1.x + w1 * s1.y + w2 * s1.z + w3 * s1.w;
      p2 += w0 * s2.x + w1 * s2.y + w2 * s2.z + w3 * s2.w;
      p3 += w0 * s3.x + w1 * s3.y + w2 * s3.z + w3 * s3.w;
    }
    red[q][0][j] = p0; red[q][1][j] = p1; red[q][2][j] = p2; red[q][3][j] = p3;
  }
  __syncthreads();
  {
    const int tt = tid >> 6, jj = tid & 63;
    float xv = red[0][tt][jj] + red[1][tt][jj] + red[2][tt][jj] + red[3][tt][jj];
    sxd[tt][jj] = xv;
    xdg[(size_t)(t0 + tt) * 64 + jj] = xv;
  }
  __syncthreads();

  // ---- phase 3: dt (coalesced dtwT reads, no staging, no barriers) ----
#pragma unroll
  for (int c = 0; c < 4; ++c) {
    const int d = c * 256 + tid;
    const float bias = dtb_p[d];
    float a0 = bias, a1 = bias, a2 = bias, a3 = bias;
    const float* wp = dtwT + d;
#pragma unroll
    for (int k = 0; k < 32; ++k) {
      const float wk = wp[(size_t)k * 1024];
      a0 += sxd[0][k] * wk;
      a1 += sxd[1][k] * wk;
      a2 += sxd[2][k] * wk;
      a3 += sxd[3][k] * wk;
    }
    dtg[(size_t)(t0 + 0) * 1024 + d] = softplus_fast(a0);
    dtg[(size_t)(t0 + 1) * 1024 + d] = softplus_fast(a1);
    dtg[(size_t)(t0 + 2) * 1024 + d] = softplus_fast(a2);
    dtg[(size_t)(t0 + 3) * 1024 + d] = softplus_fast(a3);
  }
}

// ---------------------------------------------------------------------------
// Selective scan, 4-way state split: thread = (b, d, n-quad), 4 states each.
// ---------------------------------------------------------------------------
__global__ __launch_bounds__(256)
void scan_kernel(const float* __restrict__ dtg, const float* __restrict__ xcg,
                 const float* __restrict__ xz, const float* __restrict__ xdg,
                 const float* __restrict__ A_log, const float* __restrict__ Dp,
                 unsigned short* __restrict__ y) {
  const int tid = threadIdx.x;
  const int lane = tid & 63, w = tid >> 6;
  const int nq = lane & 3, dl = lane >> 2;
  const int b = blockIdx.y;
  const int d = blockIdx.x * 64 + w * 16 + dl;

  float4 a4 = *(const float4*)(A_log + (size_t)d * 16 + nq * 4);
  float Av0 = -__expf(a4.x), Av1 = -__expf(a4.y), Av2 = -__expf(a4.z), Av3 = -__expf(a4.w);
  float h0 = 0.f, h1 = 0.f, h2 = 0.f, h3 = 0.f;
  const float Dv = Dp[d];

  const size_t tok0 = (size_t)b * LSEQ;
  float dt_n = dtg[tok0 * 1024 + d];
  float xc_n = xcg[tok0 * 1024 + d];
  float z_n  = xz[tok0 * 2048 + 1024 + d];
  float4 B_n = *(const float4*)(xdg + tok0 * 64 + 32 + nq * 4);
  float4 C_n = *(const float4*)(xdg + tok0 * 64 + 48 + nq * 4);

  for (int t = 0; t < LSEQ; ++t) {
    const float dtv = dt_n, xcv = xc_n, zv = z_n;
    const float4 Bv = B_n, Cv = C_n;
    const int tn = (t < LSEQ - 1) ? t + 1 : t;
    const size_t tk2 = tok0 + tn;
    dt_n = dtg[tk2 * 1024 + d];
    xc_n = xcg[tk2 * 1024 + d];
    z_n  = xz[tk2 * 2048 + 1024 + d];
    B_n = *(const float4*)(xdg + tk2 * 64 + 32 + nq * 4);
    C_n = *(const float4*)(xdg + tk2 * 64 + 48 + nq * 4);

    const float dtxc = dtv * xcv;
    h0 = __expf(dtv * Av0) * h0 + dtxc * Bv.x;
    float yp = h0 * Cv.x;
    h1 = __expf(dtv * Av1) * h1 + dtxc * Bv.y;
    yp += h1 * Cv.y;
    h2 = __expf(dtv * Av2) * h2 + dtxc * Bv.z;
    yp += h2 * Cv.z;
    h3 = __expf(dtv * Av3) * h3 + dtxc * Bv.w;
    yp += h3 * Cv.w;

    yp += __shfl_xor(yp, 1, 64);
    yp += __shfl_xor(yp, 2, 64);

    if (nq == 0) {
      float yv = (yp + Dv * xcv) * (zv / (1.f + __expf(-zv)));
      y[(tok0 + t) * 1024 + d] = f2bf(yv);
    }
  }
}

// ---------------------------------------------------------------------------
// Head
// ---------------------------------------------------------------------------
__global__ __launch_bounds__(256)
void head1(const float* __restrict__ a, const float* __restrict__ W,
           const float* __restrict__ bias, float* __restrict__ o) {
  const int gid = blockIdx.x * 256 + threadIdx.x;  // 32*512
  const int bb = gid >> 9, m = gid & 511;
  const float* ar = a + (size_t)bb * 512;
  const float* wr = W + (size_t)m * 512;
  float acc = bias[m];
  for (int k = 0; k < 512; k += 4) {
    float4 av = *(const float4*)(ar + k);
    float4 wv = *(const float4*)(wr + k);
    acc += av.x * wv.x + av.y * wv.y + av.z * wv.z + av.w * wv.w;
  }
  o[gid] = 0.5f * acc * (1.f + erff(acc * 0.7071067811865475f));
}

__global__ __launch_bounds__(256)
void head2(const float* __restrict__ hid, const float* __restrict__ W,
           const float* __restrict__ bias, float* __restrict__ o) {
  const int gid = blockIdx.x * 256 + threadIdx.x;  // 32*128
  const int bb = gid >> 7, m = gid & 127;
  const float* ar = hid + (size_t)bb * 512;
  const float* wr = W + (size_t)m * 512;
  float acc = bias[m];
  for (int k = 0; k < 512; k += 4) {
    float4 av = *(const float4*)(ar + k);
    float4 wv = *(const float4*)(wr + k);
    acc += av.x * wv.x + av.y * wv.y + av.z * wv.z + av.w * wv.w;
  }
  o[gid] = acc;
}

// ---------------------------------------------------------------------------
extern "C" void kernel_launch(void* const* d_in, const int* in_sizes, int n_in,
                              void* d_out, int out_size, void* d_ws, size_t ws_size,
                              hipStream_t stream) {
  const float* x      = (const float*)d_in[0];
  const float* inp_w  = (const float*)d_in[1];
  const float* inp_b  = (const float*)d_in[2];
  const float* pos    = (const float*)d_in[3];
  const float* norm_g = (const float*)d_in[4];
  const float* norm_b = (const float*)d_in[5];
  const float* in_w   = (const float*)d_in[6];
  const float* conv_w = (const float*)d_in[7];
  const float* conv_b = (const float*)d_in[8];
  const float* xproj_w= (const float*)d_in[9];
  const float* dt_w   = (const float*)d_in[10];
  const float* dt_b   = (const float*)d_in[11];
  const float* A_log  = (const float*)d_in[12];
  const float* Dp     = (const float*)d_in[13];
  const float* out_w  = (const float*)d_in[14];
  const float* lnf_g  = (const float*)d_in[15];
  const float* lnf_b  = (const float*)d_in[16];
  const float* op1_w  = (const float*)d_in[17];
  const float* op1_b  = (const float*)d_in[18];
  const float* op2_w  = (const float*)d_in[19];
  const float* op2_b  = (const float*)d_in[20];
  float* out = (float*)d_out;

  // workspace layout
  float* h      = (float*)d_ws;                       // NTOK*512
  float* xz     = h      + (size_t)NTOK * 512;        // NTOK*2048
  float* xc     = xz     + (size_t)NTOK * 2048;       // NTOK*1024
  float* xd     = xc     + (size_t)NTOK * 1024;       // NTOK*64
  float* dtb    = xd     + (size_t)NTOK * 64;         // NTOK*1024
  float* lastln = dtb    + (size_t)NTOK * 1024;       // 32*512
  float* hid    = lastln + (size_t)32 * 512;          // 32*512
  float* xpwT   = hid    + (size_t)32 * 512;          // 6*1024*64
  float* dtwT   = xpwT   + (size_t)6 * 65536;         // 6*32*1024
  unsigned short* hn_bf  = (unsigned short*)(dtwT + (size_t)6 * 32768);   // NTOK*512
  unsigned short* yb_bf  = hn_bf + (size_t)NTOK * 512;                    // NTOK*1024
  unsigned short* win_bf = yb_bf + (size_t)NTOK * 1024;                   // 2048*512
  unsigned short* wout_bf= win_bf + (size_t)2048 * 512;                   // 512*1024

  // one-time prep: weight transposes (all layers) + input projection
  xpose_xpw<<<dim3(16, 6), 256, 0, stream>>>(xproj_w, xpwT);
  xpose_dtw<<<768, 256, 0, stream>>>(dt_w, dtwT);
  gemm_nt<<<dim3(50, 8), 64, 0, stream>>>(x, inp_w, h, NTOK, 512, 142, inp_b, pos);

  for (int i = 0; i < 6; ++i) {
    f2bf_kernel<<<1024, 256, 0, stream>>>(in_w + (size_t)i * 2048 * 512, win_bf, 2048 * 512);
    f2bf_kernel<<<512, 256, 0, stream>>>(out_w + (size_t)i * 512 * 1024, wout_bf, 512 * 1024);

    ln_kernel<<<NTOK, 256, 0, stream>>>(h, nullptr, hn_bf,
                                        norm_g + (size_t)i * 512,
                                        norm_b + (size_t)i * 512, 512);
    gemm_bf16<<<dim3(25, 16), 256, 0, stream>>>(hn_bf, win_bf, xz,
                                                NTOK, 2048, 512, 0);
    mid_kernel<<<800, 256, 0, stream>>>(xz,
                                        xpwT + (size_t)i * 65536,
                                        dtwT + (size_t)i * 32768,
                                        dt_b + (size_t)i * 1024,
                                        conv_w + (size_t)i * 1024 * 4,
                                        conv_b + (size_t)i * 1024,
                                        xc, xd, dtb);
    scan_kernel<<<dim3(16, 32), 256, 0, stream>>>(dtb, xc, xz, xd,
                                                  A_log + (size_t)i * 1024 * 16,
                                                  Dp + (size_t)i * 1024, yb_bf);
    gemm_bf16<<<dim3(25, 4), 256, 0, stream>>>(yb_bf, wout_bf, h,
                                               NTOK, 512, 1024, 1);
  }

  ln_kernel<<<32, 256, 0, stream>>>(h + (size_t)(LSEQ - 1) * 512, lastln, nullptr,
                                    lnf_g, lnf_b, (long)LSEQ * 512);
  head1<<<64, 256, 0, stream>>>(lastln, op1_w, op1_b, hid);
  head2<<<16, 256, 0, stream>>>(hid, op2_w, op2_b, out);
}

// Round 5
// 1041.762 us; speedup vs baseline: 3.1417x; 1.1556x over previous
//
#include <hip/hip_runtime.h>
#include <cmath>

// Model dims (fixed)
#define LSEQ 100
#define NTOK 3200   // B*L = 32*100

typedef __attribute__((ext_vector_type(8))) short bf16x8;   // 8 bf16 (4 VGPRs)
typedef __attribute__((ext_vector_type(4))) float f32x4;

__device__ inline unsigned short f2bf(float f) {
  union { float f; unsigned u; } v; v.f = f;
  unsigned r = v.u + 0x7FFF + ((v.u >> 16) & 1);   // round-nearest-even
  return (unsigned short)(r >> 16);
}
__device__ inline float bf2f(unsigned short u) {
  union { unsigned u; float f; } v; v.u = (unsigned)u << 16; return v.f;
}
__device__ inline float softplus_fast(float x) {
  return (x > 8.f) ? x : __logf(1.f + __expf(x));
}

__device__ inline void async_ld16(const unsigned short* g, unsigned short* l) {
  __builtin_amdgcn_global_load_lds(
      (const __attribute__((address_space(1))) unsigned int*)g,
      (__attribute__((address_space(3))) unsigned int*)l,
      16, 0, 0);
}

// ---------------------------------------------------------------------------
// bf16 MFMA GEMM: C[M,N] (+)= A[M,K] @ W[N,K]^T, fp32 accumulate.
// 128x128 tile, BK=32, 256 thr (4 waves, 2x2 of 64x64), 16x16x32 MFMA.
// mode 0: fp32 store ; mode 1: fp32 accumulate ; mode 2: bf16 store
// ---------------------------------------------------------------------------
__global__ __launch_bounds__(256)
void gemm_bf16(const unsigned short* __restrict__ A,
               const unsigned short* __restrict__ Wt,
               void* __restrict__ C, int M, int N, int K, int mode) {
  __shared__ unsigned short As[128 * 32];
  __shared__ unsigned short Bs[128 * 32];
  const int tid = threadIdx.x;
  const int lane = tid & 63, w = tid >> 6;
  const int row0 = blockIdx.x * 128, col0 = blockIdx.y * 128;

  f32x4 acc[4][4];
#pragma unroll
  for (int i = 0; i < 4; ++i)
#pragma unroll
    for (int j = 0; j < 4; ++j) acc[i][j] = (f32x4){0.f, 0.f, 0.f, 0.f};

  const unsigned short* gA = A  + (size_t)(row0 + (tid >> 2)) * K + (tid & 3) * 8;
  const unsigned short* gB = Wt + (size_t)(col0 + (tid >> 2)) * K + (tid & 3) * 8;
  const size_t stride64 = (size_t)64 * K;
  unsigned short* lA = As + w * 512;
  unsigned short* lB = Bs + w * 512;

  const int mw = (w & 1) * 64, nw = (w >> 1) * 64;
  const int frow = lane & 15, fk = (lane >> 4) * 8;

  for (int k0 = 0; k0 < K; k0 += 32) {
    async_ld16(gA, lA);
    async_ld16(gA + stride64, lA + 2048);
    async_ld16(gB, lB);
    async_ld16(gB + stride64, lB + 2048);
    gA += 32; gB += 32;
    __syncthreads();

    bf16x8 af[4], bf[4];
#pragma unroll
    for (int i = 0; i < 4; ++i)
      af[i] = *(const bf16x8*)&As[(mw + i * 16 + frow) * 32 + fk];
#pragma unroll
    for (int j = 0; j < 4; ++j)
      bf[j] = *(const bf16x8*)&Bs[(nw + j * 16 + frow) * 32 + fk];
#pragma unroll
    for (int i = 0; i < 4; ++i)
#pragma unroll
      for (int j = 0; j < 4; ++j)
        acc[i][j] = __builtin_amdgcn_mfma_f32_16x16x32_bf16(af[i], bf[j], acc[i][j], 0, 0, 0);
    __syncthreads();
  }

  const int ccol = lane & 15, rq = (lane >> 4) * 4;
#pragma unroll
  for (int i = 0; i < 4; ++i) {
#pragma unroll
    for (int r = 0; r < 4; ++r) {
      const int row = row0 + mw + i * 16 + rq + r;
      if (mode == 2) {
        unsigned short* crow = (unsigned short*)C + (size_t)row * N + col0 + nw + ccol;
#pragma unroll
        for (int j = 0; j < 4; ++j) crow[j * 16] = f2bf(acc[i][j][r]);
      } else {
        float* crow = (float*)C + (size_t)row * N + col0 + nw + ccol;
#pragma unroll
        for (int j = 0; j < 4; ++j) {
          float v = acc[i][j][r];
          if (mode == 1) v += crow[j * 16];
          crow[j * 16] = v;
        }
      }
    }
  }
}

// ---------------------------------------------------------------------------
// fp32 GEMM (input projection, K=142): C = A@W^T + bias + pos
// ---------------------------------------------------------------------------
__global__ __launch_bounds__(64)
void gemm_nt(const float* __restrict__ A, const float* __restrict__ W,
             float* __restrict__ C, int M, int N, int K,
             const float* __restrict__ bias, const float* __restrict__ pos) {
  __shared__ float As[16][64];
  __shared__ float Bs[16][64];
  const int tid = threadIdx.x;
  const int row0 = blockIdx.x * 64, col0 = blockIdx.y * 64;
  float acc[8][8];
#pragma unroll
  for (int i = 0; i < 8; ++i)
#pragma unroll
    for (int j = 0; j < 8; ++j) acc[i][j] = 0.f;

  for (int k0 = 0; k0 < K; k0 += 16) {
#pragma unroll
    for (int c = 0; c < 4; ++c) {
      const int chunk = tid + c * 64;
      const int r  = chunk >> 2;
      const int kc = (chunk & 3) << 2;
      float a[4], wv[4];
#pragma unroll
      for (int jj = 0; jj < 4; ++jj) {
        int kk = k0 + kc + jj;
        a[jj]  = (kk < K) ? A[(size_t)(row0 + r) * K + kk] : 0.f;
        wv[jj] = (kk < K) ? W[(size_t)(col0 + r) * K + kk] : 0.f;
      }
#pragma unroll
      for (int jj = 0; jj < 4; ++jj) { As[kc + jj][r] = a[jj]; Bs[kc + jj][r] = wv[jj]; }
    }
    __syncthreads();
    const int tm = (tid & 7) * 8, tn = (tid >> 3) * 8;
#pragma unroll
    for (int k = 0; k < 16; ++k) {
      float av[8], bv[8];
      *(float4*)&av[0] = *(const float4*)&As[k][tm];
      *(float4*)&av[4] = *(const float4*)&As[k][tm + 4];
      *(float4*)&bv[0] = *(const float4*)&Bs[k][tn];
      *(float4*)&bv[4] = *(const float4*)&Bs[k][tn + 4];
#pragma unroll
      for (int i = 0; i < 8; ++i)
#pragma unroll
        for (int j = 0; j < 8; ++j)
          acc[i][j] += av[i] * bv[j];
    }
    __syncthreads();
  }
  const int tm = (tid & 7) * 8, tn = (tid >> 3) * 8;
#pragma unroll
  for (int i = 0; i < 8; ++i) {
    const int row = row0 + tm + i;
    float* crow = C + (size_t)row * N + (col0 + tn);
#pragma unroll
    for (int j = 0; j < 8; ++j) {
      float v = acc[i][j];
      if (bias) v += bias[col0 + tn + j];
      if (pos)  v += pos[(size_t)(row % LSEQ) * N + (col0 + tn + j)];
      crow[j] = v;
    }
  }
}

// ---------------------------------------------------------------------------
// fp32 -> bf16 conversion
// ---------------------------------------------------------------------------
__global__ __launch_bounds__(256)
void f2bf_kernel(const float* __restrict__ in, unsigned short* __restrict__ out, int n) {
  int i = (blockIdx.x * 256 + threadIdx.x) * 4;
  if (i >= n) return;
  float4 v = *(const float4*)(in + i);
  ushort4 o;
  o.x = f2bf(v.x); o.y = f2bf(v.y); o.z = f2bf(v.z); o.w = f2bf(v.w);
  *(ushort4*)(out + i) = o;
}

// ---------------------------------------------------------------------------
// xproj_w repack: in [6][64][1024] (j-major) -> out float4-interleaved
// [6][256][64][4]: out[((k>>2)*64 + j)*4 + (k&3)] = in[j*1024 + k].
// Lane j then loads float4 {w[k..k+3][j]} coalesced. grid (256, 6).
// ---------------------------------------------------------------------------
__global__ __launch_bounds__(256)
void xpose_xpw(const float* __restrict__ in, float* __restrict__ out) {
  const int layer = blockIdx.y;
  const int idx = blockIdx.x * 256 + threadIdx.x;   // j*1024 + k (coalesced read)
  const int j = idx >> 10, k = idx & 1023;
  out[(size_t)layer * 65536 + (size_t)(k >> 2) * 256 + j * 4 + (k & 3)] =
      in[(size_t)layer * 65536 + idx];
}

// ---------------------------------------------------------------------------
// LayerNorm over 512 cols. bf16 out (obf) if non-null else fp32 (o).
// ---------------------------------------------------------------------------
__global__ __launch_bounds__(256)
void ln_kernel(const float* __restrict__ x, float* __restrict__ o,
               unsigned short* __restrict__ obf,
               const float* __restrict__ g, const float* __restrict__ b,
               long rowStride) {
  const int row = blockIdx.x, tid = threadIdx.x;
  const float* xr = x + (size_t)row * rowStride;
  float v0 = xr[tid], v1 = xr[tid + 256];
  float s = v0 + v1, ss = v0 * v0 + v1 * v1;
#pragma unroll
  for (int off = 32; off > 0; off >>= 1) {
    s  += __shfl_down(s, off, 64);
    ss += __shfl_down(ss, off, 64);
  }
  __shared__ float rs[4], rss[4], mb[2];
  const int wid = tid >> 6;
  if ((tid & 63) == 0) { rs[wid] = s; rss[wid] = ss; }
  __syncthreads();
  if (tid == 0) {
    float S = rs[0] + rs[1] + rs[2] + rs[3];
    float SS = rss[0] + rss[1] + rss[2] + rss[3];
    float m = S * (1.f / 512.f);
    float var = SS * (1.f / 512.f) - m * m;
    mb[0] = m; mb[1] = rsqrtf(var + 1e-5f);
  }
  __syncthreads();
  const float m = mb[0], r = mb[1];
  float y0 = (v0 - m) * r * g[tid] + b[tid];
  float y1 = (v1 - m) * r * g[tid + 256] + b[tid + 256];
  if (obf) {
    obf[(size_t)row * 512 + tid]       = f2bf(y0);
    obf[(size_t)row * 512 + tid + 256] = f2bf(y1);
  } else {
    o[(size_t)row * 512 + tid]       = y0;
    o[(size_t)row * 512 + tid + 256] = y1;
  }
}

// ---------------------------------------------------------------------------
// Fused conv(K=4,silu) + xproj. 4 tokens/block, 256 thr. bf16 xz in,
// bf16 xc out, fp32 xd out. dt moved into scan. LDS 20 KB.
// ---------------------------------------------------------------------------
__global__ __launch_bounds__(256)
void mid_kernel(const unsigned short* __restrict__ xz,  // bf16 [NTOK][2048]
                const float* __restrict__ xpw4,         // [256][64][4] interleaved
                const float* __restrict__ cw,           // [1024][4]
                const float* __restrict__ cb,           // [1024]
                unsigned short* __restrict__ xcg,       // bf16 [NTOK][1024]
                float* __restrict__ xdg) {              // [NTOK][64]
  __shared__ float sxc[4][1024];     // 16 KB
  __shared__ float red[4][4][64];    // 4 KB
  const int tid = threadIdx.x;
  const int t0 = blockIdx.x * 4;
  const int b = t0 / LSEQ, l0 = t0 - b * LSEQ;

  // ---- phase 1: conv + silu ----
#pragma unroll
  for (int rep = 0; rep < 4; ++rep) {
    const int d = rep * 256 + tid;
    const float4 w4 = *(const float4*)(cw + (size_t)d * 4);
    const float cbv = cb[d];
    const unsigned short* base = xz + (size_t)b * LSEQ * 2048 + d;
    float v[7];
#pragma unroll
    for (int j = 0; j < 7; ++j) {
      int ls = l0 - 3 + j;
      v[j] = (ls >= 0) ? bf2f(base[(size_t)ls * 2048]) : 0.f;
    }
#pragma unroll
    for (int tt = 0; tt < 4; ++tt) {
      float a = cbv + w4.x * v[tt] + w4.y * v[tt + 1] + w4.z * v[tt + 2] + w4.w * v[tt + 3];
      a = a / (1.f + __expf(-a));
      sxc[tt][d] = a;
      xcg[(size_t)(t0 + tt) * 1024 + d] = f2bf(a);
    }
  }
  __syncthreads();

  // ---- phase 2: xproj (float4 coalesced weights, float4 LDS broadcasts) ----
  {
    const int j = tid & 63, q = tid >> 6;
    const float4* wq4 = (const float4*)xpw4;
    float p0 = 0, p1 = 0, p2 = 0, p3 = 0;
    for (int k4o = 0; k4o < 64; ++k4o) {
      const int k = q * 256 + k4o * 4;
      float4 wv = wq4[(size_t)(q * 64 + k4o) * 64 + j];
      float4 s0 = *(const float4*)&sxc[0][k];
      float4 s1 = *(const float4*)&sxc[1][k];
      float4 s2 = *(const float4*)&sxc[2][k];
      float4 s3 = *(const float4*)&sxc[3][k];
      p0 += wv.x * s0.x + wv.y * s0.y + wv.z * s0.z + wv.w * s0.w;
      p1 += wv.x * s1.x + wv.y * s1.y + wv.z * s1.z + wv.w * s1.w;
      p2 += wv.x * s2.x + wv.y * s2.y + wv.z * s2.z + wv.w * s2.w;
      p3 += wv.x * s3.x + wv.y * s3.y + wv.z * s3.z + wv.w * s3.w;
    }
    red[q][0][j] = p0; red[q][1][j] = p1; red[q][2][j] = p2; red[q][3][j] = p3;
  }
  __syncthreads();
  {
    const int tt = tid >> 6, jj = tid & 63;
    xdg[(size_t)(t0 + tt) * 64 + jj] =
        red[0][tt][jj] + red[1][tt][jj] + red[2][tt][jj] + red[3][tt][jj];
  }
}

// ---------------------------------------------------------------------------
// Selective scan with fused dt-proj, fully LDS-staged.
// Block = (64 d-values, one batch). grid (16, 32), 256 thr.
// LDS: xd[100][64] fp32 + dt[100][64] fp32 + xc[100][64] bf16 = 64000 B.
// Main 100-step loop touches only LDS/registers (z prefetched from global).
// ---------------------------------------------------------------------------
__global__ __launch_bounds__(256)
void scan_kernel(const unsigned short* __restrict__ xzg,  // bf16, z at +1024
                 const unsigned short* __restrict__ xcg,  // bf16 [NTOK][1024]
                 const float* __restrict__ xdg,           // [NTOK][64]
                 const float* __restrict__ dtw,           // [1024][32]
                 const float* __restrict__ dtb_p,         // [1024]
                 const float* __restrict__ A_log, const float* __restrict__ Dp,
                 unsigned short* __restrict__ y) {
  __shared__ float xd_l[6400];
  __shared__ float dt_l[6400];
  __shared__ unsigned short xc_l[6400];
  const int tid = threadIdx.x;
  const int d0 = blockIdx.x * 64;
  const int b  = blockIdx.y;
  const size_t tok0 = (size_t)b * LSEQ;

  // bulk coalesced preload of xd, xc
  for (int idx = tid; idx < 6400; idx += 256) {
    const int t = idx >> 6, col = idx & 63;
    xd_l[idx] = xdg[(tok0 + t) * 64 + col];
    xc_l[idx] = xcg[(tok0 + t) * 1024 + d0 + col];
  }
  __syncthreads();

  // dt phase: thread (dd, tg) computes dt for its d over 25 t values
  {
    const int dd = tid & 63, tg = tid >> 6;
    float wdt[32];
    const float* wp = dtw + (size_t)(d0 + dd) * 32;
#pragma unroll
    for (int k = 0; k < 32; k += 4) {
      float4 w4 = *(const float4*)(wp + k);
      wdt[k] = w4.x; wdt[k + 1] = w4.y; wdt[k + 2] = w4.z; wdt[k + 3] = w4.w;
    }
    const float bias = dtb_p[d0 + dd];
    for (int i = 0; i < 25; ++i) {
      const int t = tg + i * 4;
      const float* xr = &xd_l[t * 64];
      float acc = bias;
#pragma unroll
      for (int k = 0; k < 32; ++k) acc += xr[k] * wdt[k];
      dt_l[t * 64 + dd] = softplus_fast(acc);
    }
  }
  __syncthreads();

  // main scan: lane = (nq, dl); 4 states per lane
  const int lane = tid & 63, w = tid >> 6;
  const int nq = lane & 3, dl = lane >> 2;
  const int dloc = w * 16 + dl;
  const int d = d0 + dloc;

  float4 a4 = *(const float4*)(A_log + (size_t)d * 16 + nq * 4);
  float Av0 = -__expf(a4.x), Av1 = -__expf(a4.y), Av2 = -__expf(a4.z), Av3 = -__expf(a4.w);
  float h0 = 0.f, h1 = 0.f, h2 = 0.f, h3 = 0.f;
  const float Dv = Dp[d];

  const unsigned short* zp = xzg + tok0 * 2048 + 1024 + d;
  float z_n = bf2f(zp[0]);

  for (int t = 0; t < LSEQ; ++t) {
    const float zv = z_n;
    if (t < LSEQ - 1) z_n = bf2f(zp[(size_t)(t + 1) * 2048]);
    const float dtv = dt_l[t * 64 + dloc];
    const float xcv = bf2f(xc_l[t * 64 + dloc]);
    f32x4 Bv = *(const f32x4*)&xd_l[t * 64 + 32 + nq * 4];
    f32x4 Cv = *(const f32x4*)&xd_l[t * 64 + 48 + nq * 4];

    const float dtxc = dtv * xcv;
    h0 = __expf(dtv * Av0) * h0 + dtxc * Bv[0];
    float yp = h0 * Cv[0];
    h1 = __expf(dtv * Av1) * h1 + dtxc * Bv[1];
    yp += h1 * Cv[1];
    h2 = __expf(dtv * Av2) * h2 + dtxc * Bv[2];
    yp += h2 * Cv[2];
    h3 = __expf(dtv * Av3) * h3 + dtxc * Bv[3];
    yp += h3 * Cv[3];

    yp += __shfl_xor(yp, 1, 64);
    yp += __shfl_xor(yp, 2, 64);

    if (nq == 0) {
      float yv = (yp + Dv * xcv) * (zv / (1.f + __expf(-zv)));
      y[(tok0 + t) * 1024 + d] = f2bf(yv);
    }
  }
}

// ---------------------------------------------------------------------------
// Head
// ---------------------------------------------------------------------------
__global__ __launch_bounds__(256)
void head1(const float* __restrict__ a, const float* __restrict__ W,
           const float* __restrict__ bias, float* __restrict__ o) {
  const int gid = blockIdx.x * 256 + threadIdx.x;  // 32*512
  const int bb = gid >> 9, m = gid & 511;
  const float* ar = a + (size_t)bb * 512;
  const float* wr = W + (size_t)m * 512;
  float acc = bias[m];
  for (int k = 0; k < 512; k += 4) {
    float4 av = *(const float4*)(ar + k);
    float4 wv = *(const float4*)(wr + k);
    acc += av.x * wv.x + av.y * wv.y + av.z * wv.z + av.w * wv.w;
  }
  o[gid] = 0.5f * acc * (1.f + erff(acc * 0.7071067811865475f));
}

__global__ __launch_bounds__(256)
void head2(const float* __restrict__ hid, const float* __restrict__ W,
           const float* __restrict__ bias, float* __restrict__ o) {
  const int gid = blockIdx.x * 256 + threadIdx.x;  // 32*128
  const int bb = gid >> 7, m = gid & 127;
  const float* ar = hid + (size_t)bb * 512;
  const float* wr = W + (size_t)m * 512;
  float acc = bias[m];
  for (int k = 0; k < 512; k += 4) {
    float4 av = *(const float4*)(ar + k);
    float4 wv = *(const float4*)(wr + k);
    acc += av.x * wv.x + av.y * wv.y + av.z * wv.z + av.w * wv.w;
  }
  o[gid] = acc;
}

// ---------------------------------------------------------------------------
extern "C" void kernel_launch(void* const* d_in, const int* in_sizes, int n_in,
                              void* d_out, int out_size, void* d_ws, size_t ws_size,
                              hipStream_t stream) {
  const float* x      = (const float*)d_in[0];
  const float* inp_w  = (const float*)d_in[1];
  const float* inp_b  = (const float*)d_in[2];
  const float* pos    = (const float*)d_in[3];
  const float* norm_g = (const float*)d_in[4];
  const float* norm_b = (const float*)d_in[5];
  const float* in_w   = (const float*)d_in[6];
  const float* conv_w = (const float*)d_in[7];
  const float* conv_b = (const float*)d_in[8];
  const float* xproj_w= (const float*)d_in[9];
  const float* dt_w   = (const float*)d_in[10];
  const float* dt_b   = (const float*)d_in[11];
  const float* A_log  = (const float*)d_in[12];
  const float* Dp     = (const float*)d_in[13];
  const float* out_w  = (const float*)d_in[14];
  const float* lnf_g  = (const float*)d_in[15];
  const float* lnf_b  = (const float*)d_in[16];
  const float* op1_w  = (const float*)d_in[17];
  const float* op1_b  = (const float*)d_in[18];
  const float* op2_w  = (const float*)d_in[19];
  const float* op2_b  = (const float*)d_in[20];
  float* out = (float*)d_out;

  // workspace layout: fp32 arrays first, then 16B-aligned bf16 arrays
  float* h      = (float*)d_ws;                       // NTOK*512
  float* xd     = h      + (size_t)NTOK * 512;        // NTOK*64
  float* lastln = xd     + (size_t)NTOK * 64;         // 32*512
  float* hid    = lastln + (size_t)32 * 512;          // 32*512
  float* xpw4   = hid    + (size_t)32 * 512;          // 6*65536
  unsigned short* xz_bf  = (unsigned short*)(xpw4 + (size_t)6 * 65536);   // NTOK*2048
  unsigned short* xc_bf  = xz_bf  + (size_t)NTOK * 2048;                  // NTOK*1024
  unsigned short* hn_bf  = xc_bf  + (size_t)NTOK * 1024;                  // NTOK*512
  unsigned short* yb_bf  = hn_bf  + (size_t)NTOK * 512;                   // NTOK*1024
  unsigned short* win_bf = yb_bf  + (size_t)NTOK * 1024;                  // 6*2048*512
  unsigned short* wout_bf= win_bf + (size_t)6 * 2048 * 512;               // 6*512*1024

  // one-time prep: all-layer weight conversion + xproj repack + input proj
  f2bf_kernel<<<6144, 256, 0, stream>>>(in_w,  win_bf,  6 * 2048 * 512);
  f2bf_kernel<<<3072, 256, 0, stream>>>(out_w, wout_bf, 6 * 512 * 1024);
  xpose_xpw<<<dim3(256, 6), 256, 0, stream>>>(xproj_w, xpw4);
  gemm_nt<<<dim3(50, 8), 64, 0, stream>>>(x, inp_w, h, NTOK, 512, 142, inp_b, pos);

  for (int i = 0; i < 6; ++i) {
    ln_kernel<<<NTOK, 256, 0, stream>>>(h, nullptr, hn_bf,
                                        norm_g + (size_t)i * 512,
                                        norm_b + (size_t)i * 512, 512);
    gemm_bf16<<<dim3(25, 16), 256, 0, stream>>>(hn_bf, win_bf + (size_t)i * 2048 * 512,
                                                xz_bf, NTOK, 2048, 512, 2);
    mid_kernel<<<800, 256, 0, stream>>>(xz_bf,
                                        xpw4 + (size_t)i * 65536,
                                        conv_w + (size_t)i * 1024 * 4,
                                        conv_b + (size_t)i * 1024,
                                        xc_bf, xd);
    scan_kernel<<<dim3(16, 32), 256, 0, stream>>>(xz_bf, xc_bf, xd,
                                                  dt_w + (size_t)i * 1024 * 32,
                                                  dt_b + (size_t)i * 1024,
                                                  A_log + (size_t)i * 1024 * 16,
                                                  Dp + (size_t)i * 1024, yb_bf);
    gemm_bf16<<<dim3(25, 4), 256, 0, stream>>>(yb_bf, wout_bf + (size_t)i * 512 * 1024,
                                               h, NTOK, 512, 1024, 1);
  }

  ln_kernel<<<32, 256, 0, stream>>>(h + (size_t)(LSEQ - 1) * 512, lastln, nullptr,
                                    lnf_g, lnf_b, (long)LSEQ * 512);
  head1<<<64, 256, 0, stream>>>(lastln, op1_w, op1_b, hid);
  head2<<<16, 256, 0, stream>>>(hid, op2_w, op2_b, out);
}